// Round 18
// baseline (295.242 us; speedup 1.0000x reference)
//
#include <hip/hip_runtime.h>

#define D 128
#define THRESH 0.05f
#define SCALE 50.0f
#define EPS 1e-6f
#define GP 96           // gram blocks
#define RPB 544         // K-rows per gram block (17 x 32)
#define NP2 52224       // padded K (GP*RPB), zero-filled past N
#define PGRP 24         // partials per reduce group (GP/4)
#define CAP 60          // max in-degree bucket capacity
#define PS 2            // counter stride (ints): [0]=deg_out, [1]=deg_in
#define NRANGE 4        // node ranges (LDS histogram width)
#define BB 48           // segment blocks per range
#define RMAX 12500      // max nodes per range
#define RNGP 12512      // padded staging row stride (u32 elems)

typedef __attribute__((ext_vector_type(4))) int i4v;
typedef __attribute__((ext_vector_type(4))) float f4v;
typedef _Float16 h8v __attribute__((ext_vector_type(8)));
typedef _Float16 h4v __attribute__((ext_vector_type(4)));

__device__ inline float4 ntload4(const float* p) {
    f4v v = __builtin_nontemporal_load((const f4v*)p);
    return make_float4(v.x, v.y, v.z, v.w);
}

__device__ inline void decode_grq(int bid, int& g, int& r, int& q) {
    g = bid >= (NRANGE * BB);
    int rem = g ? bid - NRANGE * BB : bid;
    r = rem & (NRANGE - 1);
    q = rem >> 2;
}

// ---------------- K1: count — LDS histogram -> non-atomic staging row ----------------
__global__ void __launch_bounds__(256) count_kernel(const int* __restrict__ src1,
                                                    const int* __restrict__ dst1,
                                                    const int* __restrict__ src2,
                                                    const int* __restrict__ dst2,
                                                    unsigned int* __restrict__ staging,
                                                    int E, int N) {
    __shared__ unsigned int cnt[RMAX];
    int g, r, q;
    decode_grq(blockIdx.x, g, r, q);
    const int* __restrict__ src = g ? src2 : src1;
    const int* __restrict__ dst = g ? dst2 : dst1;

    int rng = (N + NRANGE - 1) / NRANGE;
    int lo = r * rng;
    int hi = min(N, lo + rng);
    int nr = hi - lo;
    int seg = (E + BB - 1) / BB;
    int s0 = q * seg;
    int s1 = min(E, s0 + seg);
    int tid = threadIdx.x;

    for (int i = tid; i < nr; i += 256) cnt[i] = 0u;
    __syncthreads();

    for (int e = s0 + tid * 4; e < s1; e += 1024) {
        int ss[4], dd[4];
        if (e + 4 <= s1) {
            i4v a = *(const i4v*)(src + e);
            i4v b = *(const i4v*)(dst + e);
            ss[0] = a.x; ss[1] = a.y; ss[2] = a.z; ss[3] = a.w;
            dd[0] = b.x; dd[1] = b.y; dd[2] = b.z; dd[3] = b.w;
        } else {
#pragma unroll
            for (int c = 0; c < 4; ++c) {
                int ee = e + c;
                ss[c] = (ee < s1) ? src[ee] : -1;
                dd[c] = (ee < s1) ? dst[ee] : -1;
            }
        }
#pragma unroll
        for (int c = 0; c < 4; ++c) {
            int s = ss[c], d = dd[c];
            if (s >= lo && s < hi) atomicAdd(&cnt[s - lo], 1u);          // lo16 = out
            if (d >= lo && d < hi) atomicAdd(&cnt[d - lo], 0x10000u);    // hi16 = in
        }
    }
    __syncthreads();

    unsigned int* row = staging + (size_t)(((g * NRANGE + r) * BB) + q) * RNGP;
    for (int i = tid; i < nr; i += 256) row[i] = cnt[i];
}

// ---------------- K2: scan — per node: totals -> pad; prefix bases -> staging ----------
__global__ void scan_kernel(unsigned int* __restrict__ staging, int* __restrict__ pad1,
                            int* __restrict__ pad2, int N) {
    int t = blockIdx.x * 256 + threadIdx.x;
    if (t >= 2 * N) return;
    int g = t >= N;
    int d = g ? t - N : t;
    int rng = (N + NRANGE - 1) / NRANGE;
    int r = d / rng;
    int i = d - r * rng;
    int* __restrict__ pad = g ? pad2 : pad1;

    unsigned int* base = staging + (size_t)((g * NRANGE + r) * BB) * RNGP + i;
    unsigned int oc = 0, run = 0;
#pragma unroll 4
    for (int q = 0; q < BB; ++q) {
        unsigned int c = base[(size_t)q * RNGP];
        base[(size_t)q * RNGP] = run;
        oc += c & 0xFFFFu;
        run += c >> 16;
    }
    pad[d * PS] = (int)oc;
    pad[d * PS + 1] = (int)run;
}

// ---------------- K3: place — LDS cursors from staging, scatter bucket ----------------
__global__ void __launch_bounds__(256) place_kernel(const int* __restrict__ src1,
                                                    const int* __restrict__ dst1,
                                                    const int* __restrict__ src2,
                                                    const int* __restrict__ dst2,
                                                    const unsigned int* __restrict__ staging,
                                                    unsigned short* __restrict__ bucket1,
                                                    unsigned short* __restrict__ bucket2,
                                                    int E, int N) {
    __shared__ unsigned int cur[RMAX];
    int g, r, q;
    decode_grq(blockIdx.x, g, r, q);
    const int* __restrict__ src = g ? src2 : src1;
    const int* __restrict__ dst = g ? dst2 : dst1;
    unsigned short* __restrict__ bucket = g ? bucket2 : bucket1;

    int rng = (N + NRANGE - 1) / NRANGE;
    int lo = r * rng;
    int hi = min(N, lo + rng);
    int nr = hi - lo;
    int seg = (E + BB - 1) / BB;
    int s0 = q * seg;
    int s1 = min(E, s0 + seg);
    int tid = threadIdx.x;

    const unsigned int* row = staging + (size_t)(((g * NRANGE + r) * BB) + q) * RNGP;
    for (int i = tid; i < nr; i += 256) cur[i] = row[i];
    __syncthreads();

    for (int e = s0 + tid * 4; e < s1; e += 1024) {
        int ss[4], dd[4];
        if (e + 4 <= s1) {
            i4v a = *(const i4v*)(src + e);
            i4v b = *(const i4v*)(dst + e);
            ss[0] = a.x; ss[1] = a.y; ss[2] = a.z; ss[3] = a.w;
            dd[0] = b.x; dd[1] = b.y; dd[2] = b.z; dd[3] = b.w;
        } else {
#pragma unroll
            for (int c = 0; c < 4; ++c) {
                int ee = e + c;
                ss[c] = (ee < s1) ? src[ee] : -1;
                dd[c] = (ee < s1) ? dst[ee] : -1;
            }
        }
#pragma unroll
        for (int c = 0; c < 4; ++c) {
            int s = ss[c], d = dd[c];
            if (d >= lo && d < hi) {
                unsigned int pos = atomicAdd(&cur[d - lo], 1u);
                if (pos < CAP) bucket[(size_t)d * CAP + pos] = (unsigned short)s;
            }
        }
    }
}

// ---------------- transpose both weights: Wt[j][k] = (fp16) W[k][j] ----------------
__global__ void wtrans_kernel(const float* __restrict__ W1, const float* __restrict__ W2,
                              _Float16* __restrict__ Wt1, _Float16* __restrict__ Wt2) {
    int e = blockIdx.x * 256 + threadIdx.x;
    int h = e >= D * D;
    int rem = h ? e - D * D : e;
    int j = rem >> 7, k = rem & 127;
    const float* W = h ? W2 : W1;
    _Float16* Wt = h ? Wt2 : Wt1;
    Wt[j * D + k] = (_Float16)W[k * D + j];
}

// ---------------- dense: y = in @ W -> fp16, via 16x16x32 f16 MFMA --------------------
template <bool F32IN>
__global__ void __launch_bounds__(256) gemm_ns(const float* __restrict__ tf,
                                               const _Float16* __restrict__ th,
                                               const int* __restrict__ pad,
                                               const _Float16* __restrict__ Wt,
                                               _Float16* __restrict__ y, int N) {
    __shared__ _Float16 sA[128 * D];
    __shared__ _Float16 sB[D * D];
    int tid = threadIdx.x;
    int row0 = blockIdx.x * 128;

#pragma unroll
    for (int q = 0; q < 8; ++q) {
        int c = q * 256 + tid;
        int j = c >> 4, u = c & 15;
        h8v v = *(const h8v*)(Wt + j * D + u * 8);
        int byte = j * 256 + ((u * 16) ^ ((j & 7) << 4));
        *(h8v*)((char*)sB + byte) = v;
    }
#pragma unroll
    for (int q = 0; q < 8; ++q) {
        int c = q * 256 + tid;
        int row = c >> 4, u = c & 15;
        int gr = row0 + row;
        h8v hv = {};
        if (gr < N) {
            if (F32IN) {
                float nsv = rsqrtf(fmaxf((float)pad[gr * PS], 1.f));
                const float* p = tf + (size_t)gr * D + u * 8;
                float4 v0 = *(const float4*)p;
                float4 v1 = *(const float4*)(p + 4);
                hv[0] = (_Float16)(v0.x * nsv); hv[1] = (_Float16)(v0.y * nsv);
                hv[2] = (_Float16)(v0.z * nsv); hv[3] = (_Float16)(v0.w * nsv);
                hv[4] = (_Float16)(v1.x * nsv); hv[5] = (_Float16)(v1.y * nsv);
                hv[6] = (_Float16)(v1.z * nsv); hv[7] = (_Float16)(v1.w * nsv);
            } else {
                hv = *(const h8v*)(th + (size_t)gr * D + u * 8);
            }
        }
        int byte = row * 256 + ((u * 16) ^ ((row & 7) << 4));
        *(h8v*)((char*)sA + byte) = hv;
    }
    __syncthreads();

    int w = tid >> 6;
    int l = tid & 63;
    int l16 = l & 15, lg = l >> 4;
    f4v acc[2][8];
#pragma unroll
    for (int m = 0; m < 2; ++m)
#pragma unroll
        for (int n = 0; n < 8; ++n) acc[m][n] = (f4v){0.f, 0.f, 0.f, 0.f};

#pragma unroll
    for (int kc = 0; kc < 4; ++kc) {
        h8v a[2];
#pragma unroll
        for (int m = 0; m < 2; ++m) {
            int row = w * 32 + m * 16 + l16;
            int u = kc * 4 + lg;
            int byte = row * 256 + ((u * 16) ^ ((row & 7) << 4));
            a[m] = *(const h8v*)((const char*)sA + byte);
        }
#pragma unroll
        for (int n = 0; n < 8; ++n) {
            int j = n * 16 + l16;
            int u = kc * 4 + lg;
            int byte = j * 256 + ((u * 16) ^ ((j & 7) << 4));
            h8v b = *(const h8v*)((const char*)sB + byte);
#pragma unroll
            for (int m = 0; m < 2; ++m)
                acc[m][n] = __builtin_amdgcn_mfma_f32_16x16x32_f16(a[m], b, acc[m][n], 0, 0, 0);
        }
    }

#pragma unroll
    for (int m = 0; m < 2; ++m) {
        int rbase = row0 + w * 32 + m * 16 + lg * 4;
#pragma unroll
        for (int n = 0; n < 8; ++n) {
            int col = n * 16 + l16;
#pragma unroll
            for (int r = 0; r < 4; ++r) {
                int row = rbase + r;
                if (row < N) y[(size_t)row * D + col] = (_Float16)acc[m][n][r];
            }
        }
    }
}

// ---------------- gather: g = nd*sum(y[src]) + bias ------------------------------------
template <bool OUT16>
__global__ void gather_kernel(const unsigned short* __restrict__ bucket,
                              const int* __restrict__ pad, const _Float16* __restrict__ y,
                              const float* __restrict__ bias, float* __restrict__ zf,
                              _Float16* __restrict__ zh, int N) {
    int wave = threadIdx.x >> 6;
    int lane = threadIdx.x & 63;
    int node = blockIdx.x * 4 + wave;
    if (node >= N) return;
    int deg = pad[node * PS + 1];
    int cnt = min(deg, CAP);
    float ndv = rsqrtf(fmaxf((float)deg, 1.f));
    int sid = 0;
    if (lane < cnt) sid = bucket[(size_t)node * CAP + lane];
    int grp = lane >> 4;
    int sl = lane & 15;
    const _Float16* yp = y + sl * 8;
    float acc[8] = {0.f, 0.f, 0.f, 0.f, 0.f, 0.f, 0.f, 0.f};
    for (int j = 0; j < cnt; j += 16) {
        h8v v[4];
        float vw[4];
#pragma unroll
        for (int c = 0; c < 4; ++c) {
            int idx = j + c * 4 + grp;
            int s = __shfl(sid, idx & 63);
            vw[c] = (idx < cnt) ? 1.f : 0.f;
            v[c] = *(const h8v*)(yp + (size_t)s * D);
        }
#pragma unroll
        for (int c = 0; c < 4; ++c)
#pragma unroll
            for (int u = 0; u < 8; ++u)
                acc[u] += (float)v[c][u] * vw[c];
    }
#pragma unroll
    for (int u = 0; u < 8; ++u) {
        acc[u] += __shfl_xor(acc[u], 16);
        acc[u] += __shfl_xor(acc[u], 32);
    }
    if (grp == 0) {
        float4 b0 = *(const float4*)(bias + sl * 8);
        float4 b1 = *(const float4*)(bias + sl * 8 + 4);
        float o[8];
        o[0] = acc[0] * ndv + b0.x; o[1] = acc[1] * ndv + b0.y;
        o[2] = acc[2] * ndv + b0.z; o[3] = acc[3] * ndv + b0.w;
        o[4] = acc[4] * ndv + b1.x; o[5] = acc[5] * ndv + b1.y;
        o[6] = acc[6] * ndv + b1.z; o[7] = acc[7] * ndv + b1.w;
        if (OUT16) {
            float nsv = rsqrtf(fmaxf((float)pad[node * PS], 1.f));
            h8v hv;
#pragma unroll
            for (int u = 0; u < 8; ++u) hv[u] = (_Float16)(fmaxf(o[u], 0.f) * nsv);
            *(h8v*)(zh + (size_t)node * D + sl * 8) = hv;
        } else {
            *(float4*)(zf + (size_t)node * D + sl * 8) = make_float4(o[0], o[1], o[2], o[3]);
            *(float4*)(zf + (size_t)node * D + sl * 8 + 4) = make_float4(o[4], o[5], o[6], o[7]);
        }
    }
}

// ---------------- z transpose: zt[col][node] fp16, zero-padded to NP2 ------------------
__global__ void __launch_bounds__(256) ztrans_kernel(const float* __restrict__ z1,
                                                     const float* __restrict__ z2,
                                                     _Float16* __restrict__ zt1,
                                                     _Float16* __restrict__ zt2, int N) {
    __shared__ _Float16 tile[64][132];
    int g = blockIdx.y;
    const float* z = g ? z2 : z1;
    _Float16* zt = g ? zt2 : zt1;
    int n0 = blockIdx.x * 64;
    int tid = threadIdx.x;
#pragma unroll
    for (int it = 0; it < 8; ++it) {
        int idx = it * 256 + tid;
        int row = idx >> 5;
        int c4 = (idx & 31) * 4;
        int gr = n0 + row;
        float4 v = make_float4(0.f, 0.f, 0.f, 0.f);
        if (gr < N) v = *(const float4*)&z[(size_t)gr * D + c4];
        h4v h = {(_Float16)v.x, (_Float16)v.y, (_Float16)v.z, (_Float16)v.w};
        *(h4v*)&tile[row][c4] = h;
    }
    __syncthreads();
    int col = tid >> 1, half = tid & 1;
    _Float16 buf[32];
#pragma unroll
    for (int k = 0; k < 32; ++k) buf[k] = tile[half * 32 + k][col];
    _Float16* dst = zt + (size_t)col * NP2 + n0 + half * 32;
#pragma unroll
    for (int c = 0; c < 4; ++c) *(h8v*)(dst + c * 8) = *(const h8v*)&buf[c * 8];
}

// ---------------- Gram via MFMA from transposed fp16; dense per-block stats ------------
__global__ void __launch_bounds__(512) gram_mfma(const _Float16* __restrict__ zt1,
                                                 const _Float16* __restrict__ zt2,
                                                 float* __restrict__ part,
                                                 float* __restrict__ statpart) {
    int tid = threadIdx.x;
    int w = tid >> 6, l = tid & 63;
    int l16 = l & 15, lg = l >> 4;
    f4v acc[8];
#pragma unroll
    for (int n = 0; n < 8; ++n) acc[n] = (f4v){0.f, 0.f, 0.f, 0.f};
    float sA = 0.f, qA = 0.f, sB = 0.f, qB = 0.f;
    int r0 = blockIdx.x * RPB;
    const _Float16* ap = zt1 + (size_t)(w * 16 + l16) * NP2 + lg * 8;
#pragma unroll 1
    for (int ks = 0; ks < RPB / 32; ++ks) {
        int k0 = r0 + ks * 32;
        h8v a = *(const h8v*)(ap + k0);
#pragma unroll
        for (int j = 0; j < 8; ++j) {
            float f = (float)a[j];
            sA += f;
            qA += f * f;
        }
#pragma unroll
        for (int n = 0; n < 8; ++n) {
            h8v b = *(const h8v*)(zt2 + (size_t)(n * 16 + l16) * NP2 + k0 + lg * 8);
            if (n == w) {
#pragma unroll
                for (int j = 0; j < 8; ++j) {
                    float f = (float)b[j];
                    sB += f;
                    qB += f * f;
                }
            }
            acc[n] = __builtin_amdgcn_mfma_f32_16x16x32_f16(a, b, acc[n], 0, 0, 0);
        }
    }
    float* pb = part + (size_t)blockIdx.x * (D * D);
#pragma unroll
    for (int n = 0; n < 8; ++n)
#pragma unroll
        for (int r = 0; r < 4; ++r)
            pb[(w * 16 + lg * 4 + r) * D + n * 16 + l16] = acc[n][r];
    // reduce stats over lg, then DENSE per-block store (no atomics)
    sA += __shfl_xor(sA, 16); sA += __shfl_xor(sA, 32);
    qA += __shfl_xor(qA, 16); qA += __shfl_xor(qA, 32);
    sB += __shfl_xor(sB, 16); sB += __shfl_xor(sB, 32);
    qB += __shfl_xor(qB, 16); qB += __shfl_xor(qB, 32);
    if (lg == 0) {
        int row = w * 16 + l16;
        float* sp = statpart + (size_t)blockIdx.x * 512;
        sp[row] = sA;
        sp[D + row] = qA;
        sp[2 * D + row] = sB;
        sp[3 * D + row] = qB;
    }
}

// ---------------- parallel partial reduce ----------------
__global__ void reduce_part(const float* __restrict__ part, float* __restrict__ Csum) {
    int e = blockIdx.x * 256 + threadIdx.x;
    int p0 = blockIdx.y * PGRP;
    float s = 0.f;
#pragma unroll
    for (int p = 0; p < PGRP; ++p)
        s += __builtin_nontemporal_load(&part[(size_t)(p0 + p) * (D * D) + e]);
    atomicAdd(&Csum[e], s);
}

// ---------------- fused: stats-reduce + normalize + row/col means + masks + write ------
__global__ void __launch_bounds__(1024) corrmask_kernel(const float* __restrict__ Csum,
                                                        const float* __restrict__ statpart,
                                                        const float* __restrict__ roff,
                                                        const float* __restrict__ coff,
                                                        float* __restrict__ out, int N) {
    __shared__ float cL[D * D];
    __shared__ float statsh[512];
    __shared__ float m1s[D], i1s[D], m2s[D], i2s[D];
    __shared__ float rowpart[D][2];
    __shared__ float colpart[8][D];
    __shared__ float rms[D], cms[D];
    int t = threadIdx.x;
    int j = t & 127, rg = t >> 7;
    // dense stats reduction over GP partials
    if (t < 512) {
        float s = 0.f;
        for (int p = 0; p < GP; ++p) s += statpart[(size_t)p * 512 + t];
        statsh[t] = s;
    }
    __syncthreads();
    float fn = (float)N;
    if (t < D) {
        float m1 = statsh[t] / fn;
        float v1 = fmaxf((statsh[D + t] - fn * m1 * m1) / (fn - 1.f), 0.f);
        m1s[t] = m1;
        i1s[t] = 1.f / (sqrtf(v1) + EPS);
    } else if (t < 2 * D) {
        int jj = t - D;
        float m2 = statsh[2 * D + jj] / fn;
        float v2 = fmaxf((statsh[3 * D + jj] - fn * m2 * m2) / (fn - 1.f), 0.f);
        m2s[jj] = m2;
        i2s[jj] = 1.f / (sqrtf(v2) + EPS);
    }
    __syncthreads();
    float b = m2s[j], vj = i2s[j];
    float invfn = 1.f / fn;
    float colacc = 0.f;
    for (int k = 0; k < 16; ++k) {
        int i = rg * 16 + k;
        int e = i * D + j;
        float c = (Csum[e] - fn * m1s[i] * b) * (i1s[i] * vj) * invfn;
        cL[e] = c;
        float a = fabsf(c);
        colacc += a;
        for (int o = 1; o < 64; o <<= 1) a += __shfl_xor(a, o);
        if ((j & 63) == 0) rowpart[i][j >> 6] = a;
    }
    colpart[rg][j] = colacc;
    __syncthreads();
    if (t < D) {
        float rs = rowpart[t][0] + rowpart[t][1];
        float rm = 1.f / (1.f + expf(-SCALE * (rs / (float)D + roff[t] - THRESH)));
        rms[t] = rm;
        out[D * D + t] = rm;
    } else if (t < 2 * D) {
        int jj = t - D;
        float cs = 0.f;
#pragma unroll
        for (int g2 = 0; g2 < 8; ++g2) cs += colpart[g2][jj];
        float cm = 1.f / (1.f + expf(-SCALE * (cs / (float)D + coff[jj] - THRESH)));
        cms[jj] = cm;
        out[D * D + D + jj] = cm;
    }
    __syncthreads();
    for (int k = 0; k < 16; ++k) {
        int i = rg * 16 + k;
        int e = i * D + j;
        out[e] = cL[e] * rms[i] * cms[j];
    }
}

extern "C" void kernel_launch(void* const* d_in, const int* in_sizes, int n_in,
                              void* d_out, int out_size, void* d_ws, size_t ws_size,
                              hipStream_t stream) {
    const float* x1 = (const float*)d_in[0];
    const float* x2 = (const float*)d_in[1];
    const int* src1 = (const int*)d_in[2];
    const int* dst1 = (const int*)d_in[3];
    const int* src2 = (const int*)d_in[4];
    const int* dst2 = (const int*)d_in[5];
    const float* W1 = (const float*)d_in[6];
    const float* b1 = (const float*)d_in[7];
    const float* W2 = (const float*)d_in[8];
    const float* b2 = (const float*)d_in[9];
    const float* roff = (const float*)d_in[10];
    const float* coff = (const float*)d_in[11];

    const int N = in_sizes[0] / D;
    const int E = in_sizes[2];

    float* ws = (float*)d_ws;
    unsigned int* staging = (unsigned int*)ws;
    _Float16* y = (_Float16*)ws;
    unsigned short* bucket1 =
        (unsigned short*)(staging + (size_t)2 * NRANGE * BB * RNGP);
    unsigned short* bucket2 = bucket1 + (size_t)N * CAP;
    int* pad1 = (int*)(bucket2 + (size_t)N * CAP);
    int* pad2 = pad1 + (size_t)N * PS;
    _Float16* Wt1 = (_Float16*)(pad2 + (size_t)N * PS);
    _Float16* Wt2 = Wt1 + D * D;
    // phase-2 (corr), aliases phase-1 from ws start:
    _Float16* zt1 = (_Float16*)ws;                     // D*NP2 fp16 = 13.4 MB
    _Float16* zt2 = zt1 + (size_t)D * NP2;             // 13.4 MB
    float* part = (float*)(zt2 + (size_t)D * NP2);     // GP*D*D = 6.3 MB
    float* Csum = part + (size_t)GP * D * D;           // D*D
    float* statpart = Csum + D * D;                    // GP*512

    float* out = (float*)d_out;
    float* z1 = out + D * D + 2 * D;
    float* z2 = z1 + (size_t)N * D;

    // atomic-free CSR build: count -> scan -> place
    count_kernel<<<2 * NRANGE * BB, 256, 0, stream>>>(src1, dst1, src2, dst2, staging, E, N);
    scan_kernel<<<(2 * N + 255) / 256, 256, 0, stream>>>(staging, pad1, pad2, N);
    place_kernel<<<2 * NRANGE * BB, 256, 0, stream>>>(src1, dst1, src2, dst2, staging,
                                                      bucket1, bucket2, E, N);
    wtrans_kernel<<<2 * D * D / 256, 256, 0, stream>>>(W1, W2, Wt1, Wt2);

    const int gblk = (N + 127) / 128;
    for (int g = 0; g < 2; ++g) {
        const float* x = g ? x2 : x1;
        float* z = g ? z2 : z1;
        _Float16* hp = (_Float16*)z;
        int* pad = g ? pad2 : pad1;
        unsigned short* bucket = g ? bucket2 : bucket1;

        gemm_ns<true><<<gblk, 256, 0, stream>>>(x, nullptr, pad, Wt1, y, N);
        gather_kernel<true><<<(N + 3) / 4, 256, 0, stream>>>(bucket, pad, y, b1, nullptr, hp, N);
        gemm_ns<false><<<gblk, 256, 0, stream>>>(nullptr, hp, pad, Wt2, y, N);
        gather_kernel<false><<<(N + 3) / 4, 256, 0, stream>>>(bucket, pad, y, b2, z, nullptr, N);
    }

    // corr phase: transpose -> MFMA gram (dense stats) -> reduce -> mask
    hipMemsetAsync(Csum, 0, sizeof(float) * D * D, stream);
    {
        dim3 tgrid(NP2 / 64, 2);
        ztrans_kernel<<<tgrid, 256, 0, stream>>>(z1, z2, zt1, zt2, N);
    }
    gram_mfma<<<GP, 512, 0, stream>>>(zt1, zt2, part, statpart);
    {
        dim3 grid(64, GP / PGRP);
        reduce_part<<<grid, 256, 0, stream>>>(part, Csum);
    }
    corrmask_kernel<<<1, 1024, 0, stream>>>(Csum, statpart, roff, coff, out, N);
}

// Round 19
// 280.782 us; speedup vs baseline: 1.0515x; 1.0515x over previous
//
#include <hip/hip_runtime.h>

#define D 128
#define THRESH 0.05f
#define SCALE 50.0f
#define EPS 1e-6f
#define GP 96           // gram K-blocks
#define CSPLIT 4        // gram column split (32 cols per block)
#define RPB 544         // K-rows per gram block (17 x 32)
#define NP2 52224       // padded K (GP*RPB), zero-filled past N
#define PGRP 24         // partials per reduce group (GP/4)
#define CAP 60          // max in-degree bucket capacity
#define PS 2            // counter stride (ints): [0]=deg_out, [1]=deg_in
#define NRANGE 4        // node ranges (LDS histogram width)
#define BB 48           // segment blocks per range
#define RMAX 12500      // max nodes per range
#define RNGP 12512      // padded staging row stride (u32 elems)

typedef __attribute__((ext_vector_type(4))) int i4v;
typedef __attribute__((ext_vector_type(4))) float f4v;
typedef _Float16 h8v __attribute__((ext_vector_type(8)));
typedef _Float16 h4v __attribute__((ext_vector_type(4)));

__device__ inline float4 ntload4(const float* p) {
    f4v v = __builtin_nontemporal_load((const f4v*)p);
    return make_float4(v.x, v.y, v.z, v.w);
}

__device__ inline void decode_grq(int bid, int& g, int& r, int& q) {
    g = bid >= (NRANGE * BB);
    int rem = g ? bid - NRANGE * BB : bid;
    r = rem & (NRANGE - 1);
    q = rem >> 2;
}

// ---------------- K1: count — LDS histogram -> non-atomic staging row ----------------
__global__ void __launch_bounds__(256) count_kernel(const int* __restrict__ src1,
                                                    const int* __restrict__ dst1,
                                                    const int* __restrict__ src2,
                                                    const int* __restrict__ dst2,
                                                    unsigned int* __restrict__ staging,
                                                    int E, int N) {
    __shared__ unsigned int cnt[RMAX];
    int g, r, q;
    decode_grq(blockIdx.x, g, r, q);
    const int* __restrict__ src = g ? src2 : src1;
    const int* __restrict__ dst = g ? dst2 : dst1;

    int rng = (N + NRANGE - 1) / NRANGE;
    int lo = r * rng;
    int hi = min(N, lo + rng);
    int nr = hi - lo;
    int seg = (E + BB - 1) / BB;
    int s0 = q * seg;
    int s1 = min(E, s0 + seg);
    int tid = threadIdx.x;

    for (int i = tid; i < nr; i += 256) cnt[i] = 0u;
    __syncthreads();

    for (int e = s0 + tid * 4; e < s1; e += 1024) {
        int ss[4], dd[4];
        if (e + 4 <= s1) {
            i4v a = *(const i4v*)(src + e);
            i4v b = *(const i4v*)(dst + e);
            ss[0] = a.x; ss[1] = a.y; ss[2] = a.z; ss[3] = a.w;
            dd[0] = b.x; dd[1] = b.y; dd[2] = b.z; dd[3] = b.w;
        } else {
#pragma unroll
            for (int c = 0; c < 4; ++c) {
                int ee = e + c;
                ss[c] = (ee < s1) ? src[ee] : -1;
                dd[c] = (ee < s1) ? dst[ee] : -1;
            }
        }
#pragma unroll
        for (int c = 0; c < 4; ++c) {
            int s = ss[c], d = dd[c];
            if (s >= lo && s < hi) atomicAdd(&cnt[s - lo], 1u);          // lo16 = out
            if (d >= lo && d < hi) atomicAdd(&cnt[d - lo], 0x10000u);    // hi16 = in
        }
    }
    __syncthreads();

    unsigned int* row = staging + (size_t)(((g * NRANGE + r) * BB) + q) * RNGP;
    for (int i = tid; i < nr; i += 256) row[i] = cnt[i];
}

// ---------------- K2: scan — per node: totals -> pad; prefix bases -> staging ----------
__global__ void scan_kernel(unsigned int* __restrict__ staging, int* __restrict__ pad1,
                            int* __restrict__ pad2, int N) {
    int t = blockIdx.x * 256 + threadIdx.x;
    if (t >= 2 * N) return;
    int g = t >= N;
    int d = g ? t - N : t;
    int rng = (N + NRANGE - 1) / NRANGE;
    int r = d / rng;
    int i = d - r * rng;
    int* __restrict__ pad = g ? pad2 : pad1;

    unsigned int* base = staging + (size_t)((g * NRANGE + r) * BB) * RNGP + i;
    unsigned int oc = 0, run = 0;
#pragma unroll 4
    for (int q = 0; q < BB; ++q) {
        unsigned int c = base[(size_t)q * RNGP];
        base[(size_t)q * RNGP] = run;
        oc += c & 0xFFFFu;
        run += c >> 16;
    }
    pad[d * PS] = (int)oc;
    pad[d * PS + 1] = (int)run;
}

// ---------------- K3: place — LDS cursors from staging, scatter bucket ----------------
__global__ void __launch_bounds__(256) place_kernel(const int* __restrict__ src1,
                                                    const int* __restrict__ dst1,
                                                    const int* __restrict__ src2,
                                                    const int* __restrict__ dst2,
                                                    const unsigned int* __restrict__ staging,
                                                    unsigned short* __restrict__ bucket1,
                                                    unsigned short* __restrict__ bucket2,
                                                    int E, int N) {
    __shared__ unsigned int cur[RMAX];
    int g, r, q;
    decode_grq(blockIdx.x, g, r, q);
    const int* __restrict__ src = g ? src2 : src1;
    const int* __restrict__ dst = g ? dst2 : dst1;
    unsigned short* __restrict__ bucket = g ? bucket2 : bucket1;

    int rng = (N + NRANGE - 1) / NRANGE;
    int lo = r * rng;
    int hi = min(N, lo + rng);
    int nr = hi - lo;
    int seg = (E + BB - 1) / BB;
    int s0 = q * seg;
    int s1 = min(E, s0 + seg);
    int tid = threadIdx.x;

    const unsigned int* row = staging + (size_t)(((g * NRANGE + r) * BB) + q) * RNGP;
    for (int i = tid; i < nr; i += 256) cur[i] = row[i];
    __syncthreads();

    for (int e = s0 + tid * 4; e < s1; e += 1024) {
        int ss[4], dd[4];
        if (e + 4 <= s1) {
            i4v a = *(const i4v*)(src + e);
            i4v b = *(const i4v*)(dst + e);
            ss[0] = a.x; ss[1] = a.y; ss[2] = a.z; ss[3] = a.w;
            dd[0] = b.x; dd[1] = b.y; dd[2] = b.z; dd[3] = b.w;
        } else {
#pragma unroll
            for (int c = 0; c < 4; ++c) {
                int ee = e + c;
                ss[c] = (ee < s1) ? src[ee] : -1;
                dd[c] = (ee < s1) ? dst[ee] : -1;
            }
        }
#pragma unroll
        for (int c = 0; c < 4; ++c) {
            int s = ss[c], d = dd[c];
            if (d >= lo && d < hi) {
                unsigned int pos = atomicAdd(&cur[d - lo], 1u);
                if (pos < CAP) bucket[(size_t)d * CAP + pos] = (unsigned short)s;
            }
        }
    }
}

// ---------------- transpose both weights: Wt[j][k] = (fp16) W[k][j] ----------------
__global__ void wtrans_kernel(const float* __restrict__ W1, const float* __restrict__ W2,
                              _Float16* __restrict__ Wt1, _Float16* __restrict__ Wt2) {
    int e = blockIdx.x * 256 + threadIdx.x;
    int h = e >= D * D;
    int rem = h ? e - D * D : e;
    int j = rem >> 7, k = rem & 127;
    const float* W = h ? W2 : W1;
    _Float16* Wt = h ? Wt2 : Wt1;
    Wt[j * D + k] = (_Float16)W[k * D + j];
}

// ---------------- dense: y = in @ W -> fp16, via 16x16x32 f16 MFMA --------------------
template <bool F32IN>
__global__ void __launch_bounds__(256) gemm_ns(const float* __restrict__ tf,
                                               const _Float16* __restrict__ th,
                                               const int* __restrict__ pad,
                                               const _Float16* __restrict__ Wt,
                                               _Float16* __restrict__ y, int N) {
    __shared__ _Float16 sA[128 * D];
    __shared__ _Float16 sB[D * D];
    int tid = threadIdx.x;
    int row0 = blockIdx.x * 128;

#pragma unroll
    for (int q = 0; q < 8; ++q) {
        int c = q * 256 + tid;
        int j = c >> 4, u = c & 15;
        h8v v = *(const h8v*)(Wt + j * D + u * 8);
        int byte = j * 256 + ((u * 16) ^ ((j & 7) << 4));
        *(h8v*)((char*)sB + byte) = v;
    }
#pragma unroll
    for (int q = 0; q < 8; ++q) {
        int c = q * 256 + tid;
        int row = c >> 4, u = c & 15;
        int gr = row0 + row;
        h8v hv = {};
        if (gr < N) {
            if (F32IN) {
                float nsv = rsqrtf(fmaxf((float)pad[gr * PS], 1.f));
                const float* p = tf + (size_t)gr * D + u * 8;
                float4 v0 = *(const float4*)p;
                float4 v1 = *(const float4*)(p + 4);
                hv[0] = (_Float16)(v0.x * nsv); hv[1] = (_Float16)(v0.y * nsv);
                hv[2] = (_Float16)(v0.z * nsv); hv[3] = (_Float16)(v0.w * nsv);
                hv[4] = (_Float16)(v1.x * nsv); hv[5] = (_Float16)(v1.y * nsv);
                hv[6] = (_Float16)(v1.z * nsv); hv[7] = (_Float16)(v1.w * nsv);
            } else {
                hv = *(const h8v*)(th + (size_t)gr * D + u * 8);
            }
        }
        int byte = row * 256 + ((u * 16) ^ ((row & 7) << 4));
        *(h8v*)((char*)sA + byte) = hv;
    }
    __syncthreads();

    int w = tid >> 6;
    int l = tid & 63;
    int l16 = l & 15, lg = l >> 4;
    f4v acc[2][8];
#pragma unroll
    for (int m = 0; m < 2; ++m)
#pragma unroll
        for (int n = 0; n < 8; ++n) acc[m][n] = (f4v){0.f, 0.f, 0.f, 0.f};

#pragma unroll
    for (int kc = 0; kc < 4; ++kc) {
        h8v a[2];
#pragma unroll
        for (int m = 0; m < 2; ++m) {
            int row = w * 32 + m * 16 + l16;
            int u = kc * 4 + lg;
            int byte = row * 256 + ((u * 16) ^ ((row & 7) << 4));
            a[m] = *(const h8v*)((const char*)sA + byte);
        }
#pragma unroll
        for (int n = 0; n < 8; ++n) {
            int j = n * 16 + l16;
            int u = kc * 4 + lg;
            int byte = j * 256 + ((u * 16) ^ ((j & 7) << 4));
            h8v b = *(const h8v*)((const char*)sB + byte);
#pragma unroll
            for (int m = 0; m < 2; ++m)
                acc[m][n] = __builtin_amdgcn_mfma_f32_16x16x32_f16(a[m], b, acc[m][n], 0, 0, 0);
        }
    }

#pragma unroll
    for (int m = 0; m < 2; ++m) {
        int rbase = row0 + w * 32 + m * 16 + lg * 4;
#pragma unroll
        for (int n = 0; n < 8; ++n) {
            int col = n * 16 + l16;
#pragma unroll
            for (int r = 0; r < 4; ++r) {
                int row = rbase + r;
                if (row < N) y[(size_t)row * D + col] = (_Float16)acc[m][n][r];
            }
        }
    }
}

// ---------------- gather: g = nd*sum(y[src]) + bias ------------------------------------
template <bool OUT16>
__global__ void gather_kernel(const unsigned short* __restrict__ bucket,
                              const int* __restrict__ pad, const _Float16* __restrict__ y,
                              const float* __restrict__ bias, float* __restrict__ zf,
                              _Float16* __restrict__ zh, int N) {
    int wave = threadIdx.x >> 6;
    int lane = threadIdx.x & 63;
    int node = blockIdx.x * 4 + wave;
    if (node >= N) return;
    int deg = pad[node * PS + 1];
    int cnt = min(deg, CAP);
    float ndv = rsqrtf(fmaxf((float)deg, 1.f));
    int sid = 0;
    if (lane < cnt) sid = bucket[(size_t)node * CAP + lane];
    int grp = lane >> 4;
    int sl = lane & 15;
    const _Float16* yp = y + sl * 8;
    float acc[8] = {0.f, 0.f, 0.f, 0.f, 0.f, 0.f, 0.f, 0.f};
    for (int j = 0; j < cnt; j += 16) {
        h8v v[4];
        float vw[4];
#pragma unroll
        for (int c = 0; c < 4; ++c) {
            int idx = j + c * 4 + grp;
            int s = __shfl(sid, idx & 63);
            vw[c] = (idx < cnt) ? 1.f : 0.f;
            v[c] = *(const h8v*)(yp + (size_t)s * D);
        }
#pragma unroll
        for (int c = 0; c < 4; ++c)
#pragma unroll
            for (int u = 0; u < 8; ++u)
                acc[u] += (float)v[c][u] * vw[c];
    }
#pragma unroll
    for (int u = 0; u < 8; ++u) {
        acc[u] += __shfl_xor(acc[u], 16);
        acc[u] += __shfl_xor(acc[u], 32);
    }
    if (grp == 0) {
        float4 b0 = *(const float4*)(bias + sl * 8);
        float4 b1 = *(const float4*)(bias + sl * 8 + 4);
        float o[8];
        o[0] = acc[0] * ndv + b0.x; o[1] = acc[1] * ndv + b0.y;
        o[2] = acc[2] * ndv + b0.z; o[3] = acc[3] * ndv + b0.w;
        o[4] = acc[4] * ndv + b1.x; o[5] = acc[5] * ndv + b1.y;
        o[6] = acc[6] * ndv + b1.z; o[7] = acc[7] * ndv + b1.w;
        if (OUT16) {
            float nsv = rsqrtf(fmaxf((float)pad[node * PS], 1.f));
            h8v hv;
#pragma unroll
            for (int u = 0; u < 8; ++u) hv[u] = (_Float16)(fmaxf(o[u], 0.f) * nsv);
            *(h8v*)(zh + (size_t)node * D + sl * 8) = hv;
        } else {
            *(float4*)(zf + (size_t)node * D + sl * 8) = make_float4(o[0], o[1], o[2], o[3]);
            *(float4*)(zf + (size_t)node * D + sl * 8 + 4) = make_float4(o[4], o[5], o[6], o[7]);
        }
    }
}

// ---------------- z transpose: zt[col][node] fp16, zero-padded to NP2 ------------------
__global__ void __launch_bounds__(256) ztrans_kernel(const float* __restrict__ z1,
                                                     const float* __restrict__ z2,
                                                     _Float16* __restrict__ zt1,
                                                     _Float16* __restrict__ zt2, int N) {
    __shared__ _Float16 tile[64][132];
    int g = blockIdx.y;
    const float* z = g ? z2 : z1;
    _Float16* zt = g ? zt2 : zt1;
    int n0 = blockIdx.x * 64;
    int tid = threadIdx.x;
#pragma unroll
    for (int it = 0; it < 8; ++it) {
        int idx = it * 256 + tid;
        int row = idx >> 5;
        int c4 = (idx & 31) * 4;
        int gr = n0 + row;
        float4 v = make_float4(0.f, 0.f, 0.f, 0.f);
        if (gr < N) v = *(const float4*)&z[(size_t)gr * D + c4];
        h4v h = {(_Float16)v.x, (_Float16)v.y, (_Float16)v.z, (_Float16)v.w};
        *(h4v*)&tile[row][c4] = h;
    }
    __syncthreads();
    int col = tid >> 1, half = tid & 1;
    _Float16 buf[32];
#pragma unroll
    for (int k = 0; k < 32; ++k) buf[k] = tile[half * 32 + k][col];
    _Float16* dst = zt + (size_t)col * NP2 + n0 + half * 32;
#pragma unroll
    for (int c = 0; c < 4; ++c) *(h8v*)(dst + c * 8) = *(const h8v*)&buf[c * 8];
}

// ---------------- Gram via MFMA, 4-way column split; dense per-block stats -------------
// grid (GP, CSPLIT): block (kb, y) computes rows 0..127 x cols y*32..y*32+31 over
// K-range kb*RPB..+RPB. Wave w owns row-tile w; 2 col-tiles; 3 loads + 2 MFMA per K-step.
__global__ void __launch_bounds__(512) gram_mfma(const _Float16* __restrict__ zt1,
                                                 const _Float16* __restrict__ zt2,
                                                 float* __restrict__ part,
                                                 float* __restrict__ statpart) {
    int tid = threadIdx.x;
    int w = tid >> 6, l = tid & 63;
    int l16 = l & 15, lg = l >> 4;
    int cy = blockIdx.y * 32;
    f4v acc[2];
    acc[0] = (f4v){0.f, 0.f, 0.f, 0.f};
    acc[1] = (f4v){0.f, 0.f, 0.f, 0.f};
    float sA = 0.f, qA = 0.f, sB = 0.f, qB = 0.f;
    int r0 = blockIdx.x * RPB;
    const _Float16* ap = zt1 + (size_t)(w * 16 + l16) * NP2 + lg * 8;
    const _Float16* bp0 = zt2 + (size_t)(cy + l16) * NP2 + lg * 8;
    const _Float16* bp1 = zt2 + (size_t)(cy + 16 + l16) * NP2 + lg * 8;
#pragma unroll 1
    for (int ks = 0; ks < RPB / 32; ++ks) {
        int k0 = r0 + ks * 32;
        h8v a = *(const h8v*)(ap + k0);
        h8v b0 = *(const h8v*)(bp0 + k0);
        h8v b1 = *(const h8v*)(bp1 + k0);
        if (blockIdx.y == 0) {
#pragma unroll
            for (int j = 0; j < 8; ++j) {
                float f = (float)a[j];
                sA += f;
                qA += f * f;
            }
        }
        if (w < 2) {
            h8v bb = w ? b1 : b0;
#pragma unroll
            for (int j = 0; j < 8; ++j) {
                float f = (float)bb[j];
                sB += f;
                qB += f * f;
            }
        }
        acc[0] = __builtin_amdgcn_mfma_f32_16x16x32_f16(a, b0, acc[0], 0, 0, 0);
        acc[1] = __builtin_amdgcn_mfma_f32_16x16x32_f16(a, b1, acc[1], 0, 0, 0);
    }
    float* pb = part + (size_t)blockIdx.x * (D * D);
#pragma unroll
    for (int n = 0; n < 2; ++n)
#pragma unroll
        for (int r = 0; r < 4; ++r)
            pb[(w * 16 + lg * 4 + r) * D + cy + n * 16 + l16] = acc[n][r];
    // stats: reduce over lg then dense store (no atomics)
    float* sp = statpart + (size_t)blockIdx.x * 512;
    if (blockIdx.y == 0) {
        sA += __shfl_xor(sA, 16); sA += __shfl_xor(sA, 32);
        qA += __shfl_xor(qA, 16); qA += __shfl_xor(qA, 32);
        if (lg == 0) {
            int row = w * 16 + l16;
            sp[row] = sA;
            sp[D + row] = qA;
        }
    }
    if (w < 2) {
        sB += __shfl_xor(sB, 16); sB += __shfl_xor(sB, 32);
        qB += __shfl_xor(qB, 16); qB += __shfl_xor(qB, 32);
        if (lg == 0) {
            int col = cy + w * 16 + l16;
            sp[2 * D + col] = sB;
            sp[3 * D + col] = qB;
        }
    }
}

// ---------------- parallel partial reduce ----------------
__global__ void reduce_part(const float* __restrict__ part, float* __restrict__ Csum) {
    int e = blockIdx.x * 256 + threadIdx.x;
    int p0 = blockIdx.y * PGRP;
    float s = 0.f;
#pragma unroll
    for (int p = 0; p < PGRP; ++p)
        s += __builtin_nontemporal_load(&part[(size_t)(p0 + p) * (D * D) + e]);
    atomicAdd(&Csum[e], s);
}

// ---------------- fused: stats-reduce + normalize + row/col means + masks + write ------
__global__ void __launch_bounds__(1024) corrmask_kernel(const float* __restrict__ Csum,
                                                        const float* __restrict__ statpart,
                                                        const float* __restrict__ roff,
                                                        const float* __restrict__ coff,
                                                        float* __restrict__ out, int N) {
    __shared__ float cL[D * D];
    __shared__ float statsh[512];
    __shared__ float m1s[D], i1s[D], m2s[D], i2s[D];
    __shared__ float rowpart[D][2];
    __shared__ float colpart[8][D];
    __shared__ float rms[D], cms[D];
    int t = threadIdx.x;
    int j = t & 127, rg = t >> 7;
    if (t < 512) {
        float s = 0.f;
        for (int p = 0; p < GP; ++p) s += statpart[(size_t)p * 512 + t];
        statsh[t] = s;
    }
    __syncthreads();
    float fn = (float)N;
    if (t < D) {
        float m1 = statsh[t] / fn;
        float v1 = fmaxf((statsh[D + t] - fn * m1 * m1) / (fn - 1.f), 0.f);
        m1s[t] = m1;
        i1s[t] = 1.f / (sqrtf(v1) + EPS);
    } else if (t < 2 * D) {
        int jj = t - D;
        float m2 = statsh[2 * D + jj] / fn;
        float v2 = fmaxf((statsh[3 * D + jj] - fn * m2 * m2) / (fn - 1.f), 0.f);
        m2s[jj] = m2;
        i2s[jj] = 1.f / (sqrtf(v2) + EPS);
    }
    __syncthreads();
    float b = m2s[j], vj = i2s[j];
    float invfn = 1.f / fn;
    float colacc = 0.f;
    for (int k = 0; k < 16; ++k) {
        int i = rg * 16 + k;
        int e = i * D + j;
        float c = (Csum[e] - fn * m1s[i] * b) * (i1s[i] * vj) * invfn;
        cL[e] = c;
        float a = fabsf(c);
        colacc += a;
        for (int o = 1; o < 64; o <<= 1) a += __shfl_xor(a, o);
        if ((j & 63) == 0) rowpart[i][j >> 6] = a;
    }
    colpart[rg][j] = colacc;
    __syncthreads();
    if (t < D) {
        float rs = rowpart[t][0] + rowpart[t][1];
        float rm = 1.f / (1.f + expf(-SCALE * (rs / (float)D + roff[t] - THRESH)));
        rms[t] = rm;
        out[D * D + t] = rm;
    } else if (t < 2 * D) {
        int jj = t - D;
        float cs = 0.f;
#pragma unroll
        for (int g2 = 0; g2 < 8; ++g2) cs += colpart[g2][jj];
        float cm = 1.f / (1.f + expf(-SCALE * (cs / (float)D + coff[jj] - THRESH)));
        cms[jj] = cm;
        out[D * D + D + jj] = cm;
    }
    __syncthreads();
    for (int k = 0; k < 16; ++k) {
        int i = rg * 16 + k;
        int e = i * D + j;
        out[e] = cL[e] * rms[i] * cms[j];
    }
}

extern "C" void kernel_launch(void* const* d_in, const int* in_sizes, int n_in,
                              void* d_out, int out_size, void* d_ws, size_t ws_size,
                              hipStream_t stream) {
    const float* x1 = (const float*)d_in[0];
    const float* x2 = (const float*)d_in[1];
    const int* src1 = (const int*)d_in[2];
    const int* dst1 = (const int*)d_in[3];
    const int* src2 = (const int*)d_in[4];
    const int* dst2 = (const int*)d_in[5];
    const float* W1 = (const float*)d_in[6];
    const float* b1 = (const float*)d_in[7];
    const float* W2 = (const float*)d_in[8];
    const float* b2 = (const float*)d_in[9];
    const float* roff = (const float*)d_in[10];
    const float* coff = (const float*)d_in[11];

    const int N = in_sizes[0] / D;
    const int E = in_sizes[2];

    float* ws = (float*)d_ws;
    unsigned int* staging = (unsigned int*)ws;
    _Float16* y = (_Float16*)ws;
    unsigned short* bucket1 =
        (unsigned short*)(staging + (size_t)2 * NRANGE * BB * RNGP);
    unsigned short* bucket2 = bucket1 + (size_t)N * CAP;
    int* pad1 = (int*)(bucket2 + (size_t)N * CAP);
    int* pad2 = pad1 + (size_t)N * PS;
    _Float16* Wt1 = (_Float16*)(pad2 + (size_t)N * PS);
    _Float16* Wt2 = Wt1 + D * D;
    // phase-2 (corr), aliases phase-1 from ws start:
    _Float16* zt1 = (_Float16*)ws;                     // D*NP2 fp16 = 13.4 MB
    _Float16* zt2 = zt1 + (size_t)D * NP2;             // 13.4 MB
    float* part = (float*)(zt2 + (size_t)D * NP2);     // GP*D*D = 6.3 MB
    float* Csum = part + (size_t)GP * D * D;           // D*D
    float* statpart = Csum + D * D;                    // GP*512

    float* out = (float*)d_out;
    float* z1 = out + D * D + 2 * D;
    float* z2 = z1 + (size_t)N * D;

    // atomic-free CSR build: count -> scan -> place
    count_kernel<<<2 * NRANGE * BB, 256, 0, stream>>>(src1, dst1, src2, dst2, staging, E, N);
    scan_kernel<<<(2 * N + 255) / 256, 256, 0, stream>>>(staging, pad1, pad2, N);
    place_kernel<<<2 * NRANGE * BB, 256, 0, stream>>>(src1, dst1, src2, dst2, staging,
                                                      bucket1, bucket2, E, N);
    wtrans_kernel<<<2 * D * D / 256, 256, 0, stream>>>(W1, W2, Wt1, Wt2);

    const int gblk = (N + 127) / 128;
    for (int g = 0; g < 2; ++g) {
        const float* x = g ? x2 : x1;
        float* z = g ? z2 : z1;
        _Float16* hp = (_Float16*)z;
        int* pad = g ? pad2 : pad1;
        unsigned short* bucket = g ? bucket2 : bucket1;

        gemm_ns<true><<<gblk, 256, 0, stream>>>(x, nullptr, pad, Wt1, y, N);
        gather_kernel<true><<<(N + 3) / 4, 256, 0, stream>>>(bucket, pad, y, b1, nullptr, hp, N);
        gemm_ns<false><<<gblk, 256, 0, stream>>>(nullptr, hp, pad, Wt2, y, N);
        gather_kernel<false><<<(N + 3) / 4, 256, 0, stream>>>(bucket, pad, y, b2, z, nullptr, N);
    }

    // corr phase: transpose -> MFMA gram (col-split) -> reduce -> mask
    hipMemsetAsync(Csum, 0, sizeof(float) * D * D, stream);
    {
        dim3 tgrid(NP2 / 64, 2);
        ztrans_kernel<<<tgrid, 256, 0, stream>>>(z1, z2, zt1, zt2, N);
    }
    {
        dim3 ggrid(GP, CSPLIT);
        gram_mfma<<<ggrid, 512, 0, stream>>>(zt1, zt2, part, statpart);
    }
    {
        dim3 grid(64, GP / PGRP);
        reduce_part<<<grid, 256, 0, stream>>>(part, Csum);
    }
    corrmask_kernel<<<1, 1024, 0, stream>>>(Csum, statpart, roff, coff, out, N);
}

// Round 20
// 256.619 us; speedup vs baseline: 1.1505x; 1.0942x over previous
//
#include <hip/hip_runtime.h>

#define D 128
#define THRESH 0.05f
#define SCALE 50.0f
#define EPS 1e-6f
#define GP 48           // gram K-blocks
#define CSPLIT 4        // gram column split (32 cols per block)
#define RPB 1088        // K-rows per gram block (34 x 32)
#define NP2 52224       // padded K (GP*RPB), zero-filled past N
#define CAP 60          // max in-degree bucket capacity
#define PS 2            // counter stride (ints): [0]=deg_out, [1]=deg_in
#define NRANGE 4        // node ranges (LDS histogram width)
#define BB 48           // segment blocks per range
#define RMAX 12500      // max nodes per range
#define RNGP 12512      // padded staging row stride (u32 elems)

typedef __attribute__((ext_vector_type(4))) int i4v;
typedef __attribute__((ext_vector_type(4))) float f4v;
typedef _Float16 h8v __attribute__((ext_vector_type(8)));
typedef _Float16 h4v __attribute__((ext_vector_type(4)));

__device__ inline float4 ntload4(const float* p) {
    f4v v = __builtin_nontemporal_load((const f4v*)p);
    return make_float4(v.x, v.y, v.z, v.w);
}

__device__ inline void decode_grq(int bid, int& g, int& r, int& q) {
    g = bid >= (NRANGE * BB);
    int rem = g ? bid - NRANGE * BB : bid;
    r = rem & (NRANGE - 1);
    q = rem >> 2;
}

// ---------------- K1: count — LDS histogram -> non-atomic staging row ----------------
__global__ void __launch_bounds__(256) count_kernel(const int* __restrict__ src1,
                                                    const int* __restrict__ dst1,
                                                    const int* __restrict__ src2,
                                                    const int* __restrict__ dst2,
                                                    unsigned int* __restrict__ staging,
                                                    int E, int N) {
    __shared__ unsigned int cnt[RMAX];
    int g, r, q;
    decode_grq(blockIdx.x, g, r, q);
    const int* __restrict__ src = g ? src2 : src1;
    const int* __restrict__ dst = g ? dst2 : dst1;

    int rng = (N + NRANGE - 1) / NRANGE;
    int lo = r * rng;
    int hi = min(N, lo + rng);
    int nr = hi - lo;
    int seg = (E + BB - 1) / BB;
    int s0 = q * seg;
    int s1 = min(E, s0 + seg);
    int tid = threadIdx.x;

    for (int i = tid; i < nr; i += 256) cnt[i] = 0u;
    __syncthreads();

    for (int e = s0 + tid * 4; e < s1; e += 1024) {
        int ss[4], dd[4];
        if (e + 4 <= s1) {
            i4v a = *(const i4v*)(src + e);
            i4v b = *(const i4v*)(dst + e);
            ss[0] = a.x; ss[1] = a.y; ss[2] = a.z; ss[3] = a.w;
            dd[0] = b.x; dd[1] = b.y; dd[2] = b.z; dd[3] = b.w;
        } else {
#pragma unroll
            for (int c = 0; c < 4; ++c) {
                int ee = e + c;
                ss[c] = (ee < s1) ? src[ee] : -1;
                dd[c] = (ee < s1) ? dst[ee] : -1;
            }
        }
#pragma unroll
        for (int c = 0; c < 4; ++c) {
            int s = ss[c], d = dd[c];
            if (s >= lo && s < hi) atomicAdd(&cnt[s - lo], 1u);          // lo16 = out
            if (d >= lo && d < hi) atomicAdd(&cnt[d - lo], 0x10000u);    // hi16 = in
        }
    }
    __syncthreads();

    unsigned int* row = staging + (size_t)(((g * NRANGE + r) * BB) + q) * RNGP;
    for (int i = tid; i < nr; i += 256) row[i] = cnt[i];
}

// ---------------- K2: scan — per node: totals -> pad; prefix bases -> staging ----------
__global__ void scan_kernel(unsigned int* __restrict__ staging, int* __restrict__ pad1,
                            int* __restrict__ pad2, int N) {
    int t = blockIdx.x * 256 + threadIdx.x;
    if (t >= 2 * N) return;
    int g = t >= N;
    int d = g ? t - N : t;
    int rng = (N + NRANGE - 1) / NRANGE;
    int r = d / rng;
    int i = d - r * rng;
    int* __restrict__ pad = g ? pad2 : pad1;

    unsigned int* base = staging + (size_t)((g * NRANGE + r) * BB) * RNGP + i;
    unsigned int oc = 0, run = 0;
#pragma unroll 4
    for (int q = 0; q < BB; ++q) {
        unsigned int c = base[(size_t)q * RNGP];
        base[(size_t)q * RNGP] = run;
        oc += c & 0xFFFFu;
        run += c >> 16;
    }
    pad[d * PS] = (int)oc;
    pad[d * PS + 1] = (int)run;
}

// ---------------- K3: place — LDS cursors from staging, scatter bucket ----------------
__global__ void __launch_bounds__(256) place_kernel(const int* __restrict__ src1,
                                                    const int* __restrict__ dst1,
                                                    const int* __restrict__ src2,
                                                    const int* __restrict__ dst2,
                                                    const unsigned int* __restrict__ staging,
                                                    unsigned short* __restrict__ bucket1,
                                                    unsigned short* __restrict__ bucket2,
                                                    int E, int N) {
    __shared__ unsigned int cur[RMAX];
    int g, r, q;
    decode_grq(blockIdx.x, g, r, q);
    const int* __restrict__ src = g ? src2 : src1;
    const int* __restrict__ dst = g ? dst2 : dst1;
    unsigned short* __restrict__ bucket = g ? bucket2 : bucket1;

    int rng = (N + NRANGE - 1) / NRANGE;
    int lo = r * rng;
    int hi = min(N, lo + rng);
    int nr = hi - lo;
    int seg = (E + BB - 1) / BB;
    int s0 = q * seg;
    int s1 = min(E, s0 + seg);
    int tid = threadIdx.x;

    const unsigned int* row = staging + (size_t)(((g * NRANGE + r) * BB) + q) * RNGP;
    for (int i = tid; i < nr; i += 256) cur[i] = row[i];
    __syncthreads();

    for (int e = s0 + tid * 4; e < s1; e += 1024) {
        int ss[4], dd[4];
        if (e + 4 <= s1) {
            i4v a = *(const i4v*)(src + e);
            i4v b = *(const i4v*)(dst + e);
            ss[0] = a.x; ss[1] = a.y; ss[2] = a.z; ss[3] = a.w;
            dd[0] = b.x; dd[1] = b.y; dd[2] = b.z; dd[3] = b.w;
        } else {
#pragma unroll
            for (int c = 0; c < 4; ++c) {
                int ee = e + c;
                ss[c] = (ee < s1) ? src[ee] : -1;
                dd[c] = (ee < s1) ? dst[ee] : -1;
            }
        }
#pragma unroll
        for (int c = 0; c < 4; ++c) {
            int s = ss[c], d = dd[c];
            if (d >= lo && d < hi) {
                unsigned int pos = atomicAdd(&cur[d - lo], 1u);
                if (pos < CAP) bucket[(size_t)d * CAP + pos] = (unsigned short)s;
            }
        }
    }
}

// ---------------- transpose both weights: Wt[j][k] = (fp16) W[k][j] ----------------
__global__ void wtrans_kernel(const float* __restrict__ W1, const float* __restrict__ W2,
                              _Float16* __restrict__ Wt1, _Float16* __restrict__ Wt2) {
    int e = blockIdx.x * 256 + threadIdx.x;
    int h = e >= D * D;
    int rem = h ? e - D * D : e;
    int j = rem >> 7, k = rem & 127;
    const float* W = h ? W2 : W1;
    _Float16* Wt = h ? Wt2 : Wt1;
    Wt[j * D + k] = (_Float16)W[k * D + j];
}

// ---------------- dense (both graphs): y = in @ W -> fp16, 16x16x32 f16 MFMA ----------
template <bool F32IN>
__global__ void __launch_bounds__(256) gemm_ns(const float* __restrict__ tf1,
                                               const float* __restrict__ tf2,
                                               const _Float16* __restrict__ th1,
                                               const _Float16* __restrict__ th2,
                                               const int* __restrict__ pad1,
                                               const int* __restrict__ pad2,
                                               const _Float16* __restrict__ Wt,
                                               _Float16* __restrict__ y1,
                                               _Float16* __restrict__ y2, int N) {
    __shared__ _Float16 sA[128 * D];
    __shared__ _Float16 sB[D * D];
    int g = blockIdx.y;
    const float* tf = g ? tf2 : tf1;
    const _Float16* th = g ? th2 : th1;
    const int* pad = g ? pad2 : pad1;
    _Float16* y = g ? y2 : y1;
    int tid = threadIdx.x;
    int row0 = blockIdx.x * 128;

#pragma unroll
    for (int q = 0; q < 8; ++q) {
        int c = q * 256 + tid;
        int j = c >> 4, u = c & 15;
        h8v v = *(const h8v*)(Wt + j * D + u * 8);
        int byte = j * 256 + ((u * 16) ^ ((j & 7) << 4));
        *(h8v*)((char*)sB + byte) = v;
    }
#pragma unroll
    for (int q = 0; q < 8; ++q) {
        int c = q * 256 + tid;
        int row = c >> 4, u = c & 15;
        int gr = row0 + row;
        h8v hv = {};
        if (gr < N) {
            if (F32IN) {
                float nsv = rsqrtf(fmaxf((float)pad[gr * PS], 1.f));
                const float* p = tf + (size_t)gr * D + u * 8;
                float4 v0 = *(const float4*)p;
                float4 v1 = *(const float4*)(p + 4);
                hv[0] = (_Float16)(v0.x * nsv); hv[1] = (_Float16)(v0.y * nsv);
                hv[2] = (_Float16)(v0.z * nsv); hv[3] = (_Float16)(v0.w * nsv);
                hv[4] = (_Float16)(v1.x * nsv); hv[5] = (_Float16)(v1.y * nsv);
                hv[6] = (_Float16)(v1.z * nsv); hv[7] = (_Float16)(v1.w * nsv);
            } else {
                hv = *(const h8v*)(th + (size_t)gr * D + u * 8);
            }
        }
        int byte = row * 256 + ((u * 16) ^ ((row & 7) << 4));
        *(h8v*)((char*)sA + byte) = hv;
    }
    __syncthreads();

    int w = tid >> 6;
    int l = tid & 63;
    int l16 = l & 15, lg = l >> 4;
    f4v acc[2][8];
#pragma unroll
    for (int m = 0; m < 2; ++m)
#pragma unroll
        for (int n = 0; n < 8; ++n) acc[m][n] = (f4v){0.f, 0.f, 0.f, 0.f};

#pragma unroll
    for (int kc = 0; kc < 4; ++kc) {
        h8v a[2];
#pragma unroll
        for (int m = 0; m < 2; ++m) {
            int row = w * 32 + m * 16 + l16;
            int u = kc * 4 + lg;
            int byte = row * 256 + ((u * 16) ^ ((row & 7) << 4));
            a[m] = *(const h8v*)((const char*)sA + byte);
        }
#pragma unroll
        for (int n = 0; n < 8; ++n) {
            int j = n * 16 + l16;
            int u = kc * 4 + lg;
            int byte = j * 256 + ((u * 16) ^ ((j & 7) << 4));
            h8v b = *(const h8v*)((const char*)sB + byte);
#pragma unroll
            for (int m = 0; m < 2; ++m)
                acc[m][n] = __builtin_amdgcn_mfma_f32_16x16x32_f16(a[m], b, acc[m][n], 0, 0, 0);
        }
    }

#pragma unroll
    for (int m = 0; m < 2; ++m) {
        int rbase = row0 + w * 32 + m * 16 + lg * 4;
#pragma unroll
        for (int n = 0; n < 8; ++n) {
            int col = n * 16 + l16;
#pragma unroll
            for (int r = 0; r < 4; ++r) {
                int row = rbase + r;
                if (row < N) y[(size_t)row * D + col] = (_Float16)acc[m][n][r];
            }
        }
    }
}

// ---------------- gather (both graphs): g = nd*sum(y[src]) + bias ----------------------
template <bool OUT16>
__global__ void gather_kernel(const unsigned short* __restrict__ bucket1,
                              const unsigned short* __restrict__ bucket2,
                              const int* __restrict__ pad1, const int* __restrict__ pad2,
                              const _Float16* __restrict__ y1, const _Float16* __restrict__ y2,
                              const float* __restrict__ bias,
                              float* __restrict__ zf1, float* __restrict__ zf2,
                              _Float16* __restrict__ zh1, _Float16* __restrict__ zh2, int N) {
    int g = blockIdx.y;
    const unsigned short* bucket = g ? bucket2 : bucket1;
    const int* pad = g ? pad2 : pad1;
    const _Float16* y = g ? y2 : y1;
    float* zf = g ? zf2 : zf1;
    _Float16* zh = g ? zh2 : zh1;

    int wave = threadIdx.x >> 6;
    int lane = threadIdx.x & 63;
    int node = blockIdx.x * 4 + wave;
    if (node >= N) return;
    int deg = pad[node * PS + 1];
    int cnt = min(deg, CAP);
    float ndv = rsqrtf(fmaxf((float)deg, 1.f));
    int sid = 0;
    if (lane < cnt) sid = bucket[(size_t)node * CAP + lane];
    int grp = lane >> 4;
    int sl = lane & 15;
    const _Float16* yp = y + sl * 8;
    float acc[8] = {0.f, 0.f, 0.f, 0.f, 0.f, 0.f, 0.f, 0.f};
    for (int j = 0; j < cnt; j += 16) {
        h8v v[4];
        float vw[4];
#pragma unroll
        for (int c = 0; c < 4; ++c) {
            int idx = j + c * 4 + grp;
            int s = __shfl(sid, idx & 63);
            vw[c] = (idx < cnt) ? 1.f : 0.f;
            v[c] = *(const h8v*)(yp + (size_t)s * D);
        }
#pragma unroll
        for (int c = 0; c < 4; ++c)
#pragma unroll
            for (int u = 0; u < 8; ++u)
                acc[u] += (float)v[c][u] * vw[c];
    }
#pragma unroll
    for (int u = 0; u < 8; ++u) {
        acc[u] += __shfl_xor(acc[u], 16);
        acc[u] += __shfl_xor(acc[u], 32);
    }
    if (grp == 0) {
        float4 b0 = *(const float4*)(bias + sl * 8);
        float4 b1 = *(const float4*)(bias + sl * 8 + 4);
        float o[8];
        o[0] = acc[0] * ndv + b0.x; o[1] = acc[1] * ndv + b0.y;
        o[2] = acc[2] * ndv + b0.z; o[3] = acc[3] * ndv + b0.w;
        o[4] = acc[4] * ndv + b1.x; o[5] = acc[5] * ndv + b1.y;
        o[6] = acc[6] * ndv + b1.z; o[7] = acc[7] * ndv + b1.w;
        if (OUT16) {
            float nsv = rsqrtf(fmaxf((float)pad[node * PS], 1.f));
            h8v hv;
#pragma unroll
            for (int u = 0; u < 8; ++u) hv[u] = (_Float16)(fmaxf(o[u], 0.f) * nsv);
            *(h8v*)(zh + (size_t)node * D + sl * 8) = hv;
        } else {
            *(float4*)(zf + (size_t)node * D + sl * 8) = make_float4(o[0], o[1], o[2], o[3]);
            *(float4*)(zf + (size_t)node * D + sl * 8 + 4) = make_float4(o[4], o[5], o[6], o[7]);
        }
    }
}

// ---------------- z transpose: zt[col][node] fp16, zero-padded to NP2 ------------------
__global__ void __launch_bounds__(256) ztrans_kernel(const float* __restrict__ z1,
                                                     const float* __restrict__ z2,
                                                     _Float16* __restrict__ zt1,
                                                     _Float16* __restrict__ zt2, int N) {
    __shared__ _Float16 tile[64][132];
    int g = blockIdx.y;
    const float* z = g ? z2 : z1;
    _Float16* zt = g ? zt2 : zt1;
    int n0 = blockIdx.x * 64;
    int tid = threadIdx.x;
#pragma unroll
    for (int it = 0; it < 8; ++it) {
        int idx = it * 256 + tid;
        int row = idx >> 5;
        int c4 = (idx & 31) * 4;
        int gr = n0 + row;
        float4 v = make_float4(0.f, 0.f, 0.f, 0.f);
        if (gr < N) v = *(const float4*)&z[(size_t)gr * D + c4];
        h4v h = {(_Float16)v.x, (_Float16)v.y, (_Float16)v.z, (_Float16)v.w};
        *(h4v*)&tile[row][c4] = h;
    }
    __syncthreads();
    int col = tid >> 1, half = tid & 1;
    _Float16 buf[32];
#pragma unroll
    for (int k = 0; k < 32; ++k) buf[k] = tile[half * 32 + k][col];
    _Float16* dst = zt + (size_t)col * NP2 + n0 + half * 32;
#pragma unroll
    for (int c = 0; c < 4; ++c) *(h8v*)(dst + c * 8) = *(const h8v*)&buf[c * 8];
}

// ---------------- Gram via MFMA, 4-way column split; dense per-block stats -------------
__global__ void __launch_bounds__(512) gram_mfma(const _Float16* __restrict__ zt1,
                                                 const _Float16* __restrict__ zt2,
                                                 float* __restrict__ part,
                                                 float* __restrict__ statpart) {
    int tid = threadIdx.x;
    int w = tid >> 6, l = tid & 63;
    int l16 = l & 15, lg = l >> 4;
    int cy = blockIdx.y * 32;
    f4v acc[2];
    acc[0] = (f4v){0.f, 0.f, 0.f, 0.f};
    acc[1] = (f4v){0.f, 0.f, 0.f, 0.f};
    float sA = 0.f, qA = 0.f, sB = 0.f, qB = 0.f;
    int r0 = blockIdx.x * RPB;
    const _Float16* ap = zt1 + (size_t)(w * 16 + l16) * NP2 + lg * 8;
    const _Float16* bp0 = zt2 + (size_t)(cy + l16) * NP2 + lg * 8;
    const _Float16* bp1 = zt2 + (size_t)(cy + 16 + l16) * NP2 + lg * 8;
#pragma unroll 1
    for (int ks = 0; ks < RPB / 32; ++ks) {
        int k0 = r0 + ks * 32;
        h8v a = *(const h8v*)(ap + k0);
        h8v b0 = *(const h8v*)(bp0 + k0);
        h8v b1 = *(const h8v*)(bp1 + k0);
        if (blockIdx.y == 0) {
#pragma unroll
            for (int j = 0; j < 8; ++j) {
                float f = (float)a[j];
                sA += f;
                qA += f * f;
            }
        }
        if (w < 2) {
            h8v bb = w ? b1 : b0;
#pragma unroll
            for (int j = 0; j < 8; ++j) {
                float f = (float)bb[j];
                sB += f;
                qB += f * f;
            }
        }
        acc[0] = __builtin_amdgcn_mfma_f32_16x16x32_f16(a, b0, acc[0], 0, 0, 0);
        acc[1] = __builtin_amdgcn_mfma_f32_16x16x32_f16(a, b1, acc[1], 0, 0, 0);
    }
    float* pb = part + (size_t)blockIdx.x * (D * D);
#pragma unroll
    for (int n = 0; n < 2; ++n)
#pragma unroll
        for (int r = 0; r < 4; ++r)
            pb[(w * 16 + lg * 4 + r) * D + cy + n * 16 + l16] = acc[n][r];
    float* sp = statpart + (size_t)blockIdx.x * 512;
    if (blockIdx.y == 0) {
        sA += __shfl_xor(sA, 16); sA += __shfl_xor(sA, 32);
        qA += __shfl_xor(qA, 16); qA += __shfl_xor(qA, 32);
        if (lg == 0) {
            int row = w * 16 + l16;
            sp[row] = sA;
            sp[D + row] = qA;
        }
    }
    if (w < 2) {
        sB += __shfl_xor(sB, 16); sB += __shfl_xor(sB, 32);
        qB += __shfl_xor(qB, 16); qB += __shfl_xor(qB, 32);
        if (lg == 0) {
            int col = cy + w * 16 + l16;
            sp[2 * D + col] = sB;
            sp[3 * D + col] = qB;
        }
    }
}

// ---------------- single-pass partial reduce (no atomics, no memset) -------------------
__global__ void reduce_part(const float* __restrict__ part, float* __restrict__ Csum) {
    int e = blockIdx.x * 256 + threadIdx.x;
    float s = 0.f;
#pragma unroll 8
    for (int p = 0; p < GP; ++p)
        s += __builtin_nontemporal_load(&part[(size_t)p * (D * D) + e]);
    Csum[e] = s;
}

// ---------------- fused: stats-reduce + normalize + row/col means + masks + write ------
__global__ void __launch_bounds__(1024) corrmask_kernel(const float* __restrict__ Csum,
                                                        const float* __restrict__ statpart,
                                                        const float* __restrict__ roff,
                                                        const float* __restrict__ coff,
                                                        float* __restrict__ out, int N) {
    __shared__ float cL[D * D];
    __shared__ float statsh[512];
    __shared__ float m1s[D], i1s[D], m2s[D], i2s[D];
    __shared__ float rowpart[D][2];
    __shared__ float colpart[8][D];
    __shared__ float rms[D], cms[D];
    int t = threadIdx.x;
    int j = t & 127, rg = t >> 7;
    if (t < 512) {
        float s = 0.f;
        for (int p = 0; p < GP; ++p) s += statpart[(size_t)p * 512 + t];
        statsh[t] = s;
    }
    __syncthreads();
    float fn = (float)N;
    if (t < D) {
        float m1 = statsh[t] / fn;
        float v1 = fmaxf((statsh[D + t] - fn * m1 * m1) / (fn - 1.f), 0.f);
        m1s[t] = m1;
        i1s[t] = 1.f / (sqrtf(v1) + EPS);
    } else if (t < 2 * D) {
        int jj = t - D;
        float m2 = statsh[2 * D + jj] / fn;
        float v2 = fmaxf((statsh[3 * D + jj] - fn * m2 * m2) / (fn - 1.f), 0.f);
        m2s[jj] = m2;
        i2s[jj] = 1.f / (sqrtf(v2) + EPS);
    }
    __syncthreads();
    float b = m2s[j], vj = i2s[j];
    float invfn = 1.f / fn;
    float colacc = 0.f;
    for (int k = 0; k < 16; ++k) {
        int i = rg * 16 + k;
        int e = i * D + j;
        float c = (Csum[e] - fn * m1s[i] * b) * (i1s[i] * vj) * invfn;
        cL[e] = c;
        float a = fabsf(c);
        colacc += a;
        for (int o = 1; o < 64; o <<= 1) a += __shfl_xor(a, o);
        if ((j & 63) == 0) rowpart[i][j >> 6] = a;
    }
    colpart[rg][j] = colacc;
    __syncthreads();
    if (t < D) {
        float rs = rowpart[t][0] + rowpart[t][1];
        float rm = 1.f / (1.f + expf(-SCALE * (rs / (float)D + roff[t] - THRESH)));
        rms[t] = rm;
        out[D * D + t] = rm;
    } else if (t < 2 * D) {
        int jj = t - D;
        float cs = 0.f;
#pragma unroll
        for (int g2 = 0; g2 < 8; ++g2) cs += colpart[g2][jj];
        float cm = 1.f / (1.f + expf(-SCALE * (cs / (float)D + coff[jj] - THRESH)));
        cms[jj] = cm;
        out[D * D + D + jj] = cm;
    }
    __syncthreads();
    for (int k = 0; k < 16; ++k) {
        int i = rg * 16 + k;
        int e = i * D + j;
        out[e] = cL[e] * rms[i] * cms[j];
    }
}

extern "C" void kernel_launch(void* const* d_in, const int* in_sizes, int n_in,
                              void* d_out, int out_size, void* d_ws, size_t ws_size,
                              hipStream_t stream) {
    const float* x1 = (const float*)d_in[0];
    const float* x2 = (const float*)d_in[1];
    const int* src1 = (const int*)d_in[2];
    const int* dst1 = (const int*)d_in[3];
    const int* src2 = (const int*)d_in[4];
    const int* dst2 = (const int*)d_in[5];
    const float* W1 = (const float*)d_in[6];
    const float* b1 = (const float*)d_in[7];
    const float* W2 = (const float*)d_in[8];
    const float* b2 = (const float*)d_in[9];
    const float* roff = (const float*)d_in[10];
    const float* coff = (const float*)d_in[11];

    const int N = in_sizes[0] / D;
    const int E = in_sizes[2];

    float* ws = (float*)d_ws;
    // phase-1 (no aliasing; ws is 256 MB):
    unsigned int* staging = (unsigned int*)ws;                         // 19.2 MB
    unsigned short* bucket1 =
        (unsigned short*)(staging + (size_t)2 * NRANGE * BB * RNGP);   // 6 MB
    unsigned short* bucket2 = bucket1 + (size_t)N * CAP;               // 6 MB
    int* pad1 = (int*)(bucket2 + (size_t)N * CAP);                     // 0.4 MB
    int* pad2 = pad1 + (size_t)N * PS;                                 // 0.4 MB
    _Float16* Wt1 = (_Float16*)(pad2 + (size_t)N * PS);                // 32 KB
    _Float16* Wt2 = Wt1 + D * D;                                       // 32 KB
    _Float16* y1 = Wt2 + D * D;                                        // 12.8 MB
    _Float16* y2 = y1 + (size_t)N * D;                                 // 12.8 MB
    // phase-2 (aliases from ws start; phase-1 dead by then except z in d_out):
    _Float16* zt1 = (_Float16*)ws;                                     // 13.4 MB
    _Float16* zt2 = zt1 + (size_t)D * NP2;                             // 13.4 MB
    float* part = (float*)(zt2 + (size_t)D * NP2);                     // 3.1 MB
    float* Csum = part + (size_t)GP * D * D;                           // 64 KB
    float* statpart = Csum + D * D;                                    // 96 KB

    float* out = (float*)d_out;
    float* z1 = out + D * D + 2 * D;
    float* z2 = z1 + (size_t)N * D;
    _Float16* hp1 = (_Float16*)z1;   // fp16 h' scratch in z regions (dead by gather2)
    _Float16* hp2 = (_Float16*)z2;

    // atomic-free CSR build: count -> scan -> place
    count_kernel<<<2 * NRANGE * BB, 256, 0, stream>>>(src1, dst1, src2, dst2, staging, E, N);
    scan_kernel<<<(2 * N + 255) / 256, 256, 0, stream>>>(staging, pad1, pad2, N);
    place_kernel<<<2 * NRANGE * BB, 256, 0, stream>>>(src1, dst1, src2, dst2, staging,
                                                      bucket1, bucket2, E, N);
    wtrans_kernel<<<2 * D * D / 256, 256, 0, stream>>>(W1, W2, Wt1, Wt2);

    // GNN layers, both graphs per launch
    const int gblk = (N + 127) / 128;
    {
        dim3 gg(gblk, 2), ga((N + 3) / 4, 2);
        gemm_ns<true><<<gg, 256, 0, stream>>>(x1, x2, nullptr, nullptr, pad1, pad2,
                                              Wt1, y1, y2, N);
        gather_kernel<true><<<ga, 256, 0, stream>>>(bucket1, bucket2, pad1, pad2, y1, y2,
                                                    b1, nullptr, nullptr, hp1, hp2, N);
        gemm_ns<false><<<gg, 256, 0, stream>>>(nullptr, nullptr, hp1, hp2, pad1, pad2,
                                               Wt2, y1, y2, N);
        gather_kernel<false><<<ga, 256, 0, stream>>>(bucket1, bucket2, pad1, pad2, y1, y2,
                                                     b2, z1, z2, nullptr, nullptr, N);
    }

    // corr phase: transpose -> MFMA gram (col-split) -> reduce -> mask
    {
        dim3 tgrid(NP2 / 64, 2);
        ztrans_kernel<<<tgrid, 256, 0, stream>>>(z1, z2, zt1, zt2, N);
    }
    {
        dim3 ggrid(GP, CSPLIT);
        gram_mfma<<<ggrid, 512, 0, stream>>>(zt1, zt2, part, statpart);
    }
    reduce_part<<<64, 256, 0, stream>>>(part, Csum);
    corrmask_kernel<<<1, 1024, 0, stream>>>(Csum, statpart, roff, coff, out, N);
}

// Round 21
// 254.930 us; speedup vs baseline: 1.1581x; 1.0066x over previous
//
#include <hip/hip_runtime.h>

#define D 128
#define THRESH 0.05f
#define SCALE 50.0f
#define EPS 1e-6f
#define GP 48           // gram K-blocks
#define CSPLIT 4        // gram column split (32 cols per block)
#define RPB 1088        // K-rows per gram block (34 x 32)
#define NP2 52224       // padded K (GP*RPB), zero-filled past N
#define CAP 60          // max in-degree bucket capacity
#define PS 2            // counter stride (ints): [0]=deg_out, [1]=deg_in
#define NRANGE 4        // node ranges (LDS histogram width)
#define BB 48           // segment blocks per range
#define RMAX 12500      // max nodes per range
#define RNGP 12512      // padded staging row stride (u32 elems)

typedef __attribute__((ext_vector_type(4))) int i4v;
typedef __attribute__((ext_vector_type(4))) float f4v;
typedef _Float16 h8v __attribute__((ext_vector_type(8)));
typedef _Float16 h4v __attribute__((ext_vector_type(4)));

__device__ inline float4 ntload4(const float* p) {
    f4v v = __builtin_nontemporal_load((const f4v*)p);
    return make_float4(v.x, v.y, v.z, v.w);
}

__device__ inline void decode_grq(int bid, int& g, int& r, int& q) {
    g = bid >= (NRANGE * BB);
    int rem = g ? bid - NRANGE * BB : bid;
    r = rem & (NRANGE - 1);
    q = rem >> 2;
}

// ---------------- K1: count — LDS histogram -> non-atomic staging row ----------------
__global__ void __launch_bounds__(256) count_kernel(const int* __restrict__ src1,
                                                    const int* __restrict__ dst1,
                                                    const int* __restrict__ src2,
                                                    const int* __restrict__ dst2,
                                                    unsigned int* __restrict__ staging,
                                                    int E, int N) {
    __shared__ unsigned int cnt[RMAX];
    int g, r, q;
    decode_grq(blockIdx.x, g, r, q);
    const int* __restrict__ src = g ? src2 : src1;
    const int* __restrict__ dst = g ? dst2 : dst1;

    int rng = (N + NRANGE - 1) / NRANGE;
    int lo = r * rng;
    int hi = min(N, lo + rng);
    int nr = hi - lo;
    int seg = (E + BB - 1) / BB;
    int s0 = q * seg;
    int s1 = min(E, s0 + seg);
    int tid = threadIdx.x;

    for (int i = tid; i < nr; i += 256) cnt[i] = 0u;
    __syncthreads();

    for (int e = s0 + tid * 4; e < s1; e += 1024) {
        int ss[4], dd[4];
        if (e + 4 <= s1) {
            i4v a = *(const i4v*)(src + e);
            i4v b = *(const i4v*)(dst + e);
            ss[0] = a.x; ss[1] = a.y; ss[2] = a.z; ss[3] = a.w;
            dd[0] = b.x; dd[1] = b.y; dd[2] = b.z; dd[3] = b.w;
        } else {
#pragma unroll
            for (int c = 0; c < 4; ++c) {
                int ee = e + c;
                ss[c] = (ee < s1) ? src[ee] : -1;
                dd[c] = (ee < s1) ? dst[ee] : -1;
            }
        }
#pragma unroll
        for (int c = 0; c < 4; ++c) {
            int s = ss[c], d = dd[c];
            if (s >= lo && s < hi) atomicAdd(&cnt[s - lo], 1u);          // lo16 = out
            if (d >= lo && d < hi) atomicAdd(&cnt[d - lo], 0x10000u);    // hi16 = in
        }
    }
    __syncthreads();

    unsigned int* row = staging + (size_t)(((g * NRANGE + r) * BB) + q) * RNGP;
    for (int i = tid; i < nr; i += 256) row[i] = cnt[i];
}

// ---------------- K2: scan — per node: totals -> pad; prefix bases -> staging ----------
__global__ void scan_kernel(unsigned int* __restrict__ staging, int* __restrict__ pad1,
                            int* __restrict__ pad2, int N) {
    int t = blockIdx.x * 256 + threadIdx.x;
    if (t >= 2 * N) return;
    int g = t >= N;
    int d = g ? t - N : t;
    int rng = (N + NRANGE - 1) / NRANGE;
    int r = d / rng;
    int i = d - r * rng;
    int* __restrict__ pad = g ? pad2 : pad1;

    unsigned int* base = staging + (size_t)((g * NRANGE + r) * BB) * RNGP + i;
    unsigned int oc = 0, run = 0;
#pragma unroll 4
    for (int q = 0; q < BB; ++q) {
        unsigned int c = base[(size_t)q * RNGP];
        base[(size_t)q * RNGP] = run;
        oc += c & 0xFFFFu;
        run += c >> 16;
    }
    pad[d * PS] = (int)oc;
    pad[d * PS + 1] = (int)run;
}

// ---------------- K3: place — LDS cursors from staging, scatter bucket ----------------
__global__ void __launch_bounds__(256) place_kernel(const int* __restrict__ src1,
                                                    const int* __restrict__ dst1,
                                                    const int* __restrict__ src2,
                                                    const int* __restrict__ dst2,
                                                    const unsigned int* __restrict__ staging,
                                                    unsigned short* __restrict__ bucket1,
                                                    unsigned short* __restrict__ bucket2,
                                                    int E, int N) {
    __shared__ unsigned int cur[RMAX];
    int g, r, q;
    decode_grq(blockIdx.x, g, r, q);
    const int* __restrict__ src = g ? src2 : src1;
    const int* __restrict__ dst = g ? dst2 : dst1;
    unsigned short* __restrict__ bucket = g ? bucket2 : bucket1;

    int rng = (N + NRANGE - 1) / NRANGE;
    int lo = r * rng;
    int hi = min(N, lo + rng);
    int nr = hi - lo;
    int seg = (E + BB - 1) / BB;
    int s0 = q * seg;
    int s1 = min(E, s0 + seg);
    int tid = threadIdx.x;

    const unsigned int* row = staging + (size_t)(((g * NRANGE + r) * BB) + q) * RNGP;
    for (int i = tid; i < nr; i += 256) cur[i] = row[i];
    __syncthreads();

    for (int e = s0 + tid * 4; e < s1; e += 1024) {
        int ss[4], dd[4];
        if (e + 4 <= s1) {
            i4v a = *(const i4v*)(src + e);
            i4v b = *(const i4v*)(dst + e);
            ss[0] = a.x; ss[1] = a.y; ss[2] = a.z; ss[3] = a.w;
            dd[0] = b.x; dd[1] = b.y; dd[2] = b.z; dd[3] = b.w;
        } else {
#pragma unroll
            for (int c = 0; c < 4; ++c) {
                int ee = e + c;
                ss[c] = (ee < s1) ? src[ee] : -1;
                dd[c] = (ee < s1) ? dst[ee] : -1;
            }
        }
#pragma unroll
        for (int c = 0; c < 4; ++c) {
            int s = ss[c], d = dd[c];
            if (d >= lo && d < hi) {
                unsigned int pos = atomicAdd(&cur[d - lo], 1u);
                if (pos < CAP) bucket[(size_t)d * CAP + pos] = (unsigned short)s;
            }
        }
    }
}

// ---------------- weights transpose + zero sentinel rows of y1/y2 ----------------------
__global__ void wtrans_kernel(const float* __restrict__ W1, const float* __restrict__ W2,
                              _Float16* __restrict__ Wt1, _Float16* __restrict__ Wt2,
                              _Float16* __restrict__ y1, _Float16* __restrict__ y2, int N) {
    if (blockIdx.x == 2 * D * D / 256) {
        int t = threadIdx.x;
        if (t < D) y1[(size_t)N * D + t] = (_Float16)0;
        else y2[(size_t)N * D + (t - D)] = (_Float16)0;
        return;
    }
    int e = blockIdx.x * 256 + threadIdx.x;
    int h = e >= D * D;
    int rem = h ? e - D * D : e;
    int j = rem >> 7, k = rem & 127;
    const float* W = h ? W2 : W1;
    _Float16* Wt = h ? Wt2 : Wt1;
    Wt[j * D + k] = (_Float16)W[k * D + j];
}

// ---------------- dense (both graphs): y = in @ W -> fp16, 16x16x32 f16 MFMA ----------
template <bool F32IN>
__global__ void __launch_bounds__(256) gemm_ns(const float* __restrict__ tf1,
                                               const float* __restrict__ tf2,
                                               const _Float16* __restrict__ th1,
                                               const _Float16* __restrict__ th2,
                                               const int* __restrict__ pad1,
                                               const int* __restrict__ pad2,
                                               const _Float16* __restrict__ Wt,
                                               _Float16* __restrict__ y1,
                                               _Float16* __restrict__ y2, int N) {
    __shared__ _Float16 sA[128 * D];
    __shared__ _Float16 sB[D * D];
    int g = blockIdx.y;
    const float* tf = g ? tf2 : tf1;
    const _Float16* th = g ? th2 : th1;
    const int* pad = g ? pad2 : pad1;
    _Float16* y = g ? y2 : y1;
    int tid = threadIdx.x;
    int row0 = blockIdx.x * 128;

#pragma unroll
    for (int q = 0; q < 8; ++q) {
        int c = q * 256 + tid;
        int j = c >> 4, u = c & 15;
        h8v v = *(const h8v*)(Wt + j * D + u * 8);
        int byte = j * 256 + ((u * 16) ^ ((j & 7) << 4));
        *(h8v*)((char*)sB + byte) = v;
    }
#pragma unroll
    for (int q = 0; q < 8; ++q) {
        int c = q * 256 + tid;
        int row = c >> 4, u = c & 15;
        int gr = row0 + row;
        h8v hv = {};
        if (gr < N) {
            if (F32IN) {
                float nsv = rsqrtf(fmaxf((float)pad[gr * PS], 1.f));
                const float* p = tf + (size_t)gr * D + u * 8;
                float4 v0 = *(const float4*)p;
                float4 v1 = *(const float4*)(p + 4);
                hv[0] = (_Float16)(v0.x * nsv); hv[1] = (_Float16)(v0.y * nsv);
                hv[2] = (_Float16)(v0.z * nsv); hv[3] = (_Float16)(v0.w * nsv);
                hv[4] = (_Float16)(v1.x * nsv); hv[5] = (_Float16)(v1.y * nsv);
                hv[6] = (_Float16)(v1.z * nsv); hv[7] = (_Float16)(v1.w * nsv);
            } else {
                hv = *(const h8v*)(th + (size_t)gr * D + u * 8);
            }
        }
        int byte = row * 256 + ((u * 16) ^ ((row & 7) << 4));
        *(h8v*)((char*)sA + byte) = hv;
    }
    __syncthreads();

    int w = tid >> 6;
    int l = tid & 63;
    int l16 = l & 15, lg = l >> 4;
    f4v acc[2][8];
#pragma unroll
    for (int m = 0; m < 2; ++m)
#pragma unroll
        for (int n = 0; n < 8; ++n) acc[m][n] = (f4v){0.f, 0.f, 0.f, 0.f};

#pragma unroll
    for (int kc = 0; kc < 4; ++kc) {
        h8v a[2];
#pragma unroll
        for (int m = 0; m < 2; ++m) {
            int row = w * 32 + m * 16 + l16;
            int u = kc * 4 + lg;
            int byte = row * 256 + ((u * 16) ^ ((row & 7) << 4));
            a[m] = *(const h8v*)((const char*)sA + byte);
        }
#pragma unroll
        for (int n = 0; n < 8; ++n) {
            int j = n * 16 + l16;
            int u = kc * 4 + lg;
            int byte = j * 256 + ((u * 16) ^ ((j & 7) << 4));
            h8v b = *(const h8v*)((const char*)sB + byte);
#pragma unroll
            for (int m = 0; m < 2; ++m)
                acc[m][n] = __builtin_amdgcn_mfma_f32_16x16x32_f16(a[m], b, acc[m][n], 0, 0, 0);
        }
    }

#pragma unroll
    for (int m = 0; m < 2; ++m) {
        int rbase = row0 + w * 32 + m * 16 + lg * 4;
#pragma unroll
        for (int n = 0; n < 8; ++n) {
            int col = n * 16 + l16;
#pragma unroll
            for (int r = 0; r < 4; ++r) {
                int row = rbase + r;
                if (row < N) y[(size_t)row * D + col] = (_Float16)acc[m][n][r];
            }
        }
    }
}

// ---------------- gather (both graphs): g = nd*sum(y[src]) + bias ----------------------
// sentinel row N (zeros) replaces weight masking; fma_mix-friendly inner loop.
template <bool OUT16>
__global__ void gather_kernel(const unsigned short* __restrict__ bucket1,
                              const unsigned short* __restrict__ bucket2,
                              const int* __restrict__ pad1, const int* __restrict__ pad2,
                              const _Float16* __restrict__ y1, const _Float16* __restrict__ y2,
                              const float* __restrict__ bias,
                              float* __restrict__ zf1, float* __restrict__ zf2,
                              _Float16* __restrict__ zh1, _Float16* __restrict__ zh2, int N) {
    int g = blockIdx.y;
    const unsigned short* bucket = g ? bucket2 : bucket1;
    const int* pad = g ? pad2 : pad1;
    const _Float16* y = g ? y2 : y1;
    float* zf = g ? zf2 : zf1;
    _Float16* zh = g ? zh2 : zh1;

    int wave = threadIdx.x >> 6;
    int lane = threadIdx.x & 63;
    int node = blockIdx.x * 4 + wave;
    if (node >= N) return;
    int deg = pad[node * PS + 1];
    int cnt = min(deg, CAP);
    float ndv = rsqrtf(fmaxf((float)deg, 1.f));
    int sid = N;
    if (lane < cnt) sid = bucket[(size_t)node * CAP + lane];
    int grp = lane >> 4;
    int sl = lane & 15;
    const _Float16* yp = y + sl * 8;
    const h8v vone = {(_Float16)1, (_Float16)1, (_Float16)1, (_Float16)1,
                      (_Float16)1, (_Float16)1, (_Float16)1, (_Float16)1};
    float acc[8] = {0.f, 0.f, 0.f, 0.f, 0.f, 0.f, 0.f, 0.f};
    for (int j = 0; j < cnt; j += 16) {
        h8v v[4];
#pragma unroll
        for (int c = 0; c < 4; ++c) {
            int idx = j + c * 4 + grp;            // <= 63 always
            int s = __shfl(sid, idx);
            s = (idx < cnt) ? s : N;              // sentinel zero row
            v[c] = *(const h8v*)(yp + ((unsigned)s << 7));
        }
#pragma unroll
        for (int c = 0; c < 4; ++c)
#pragma unroll
            for (int u = 0; u < 8; ++u)
                acc[u] += (float)v[c][u] * (float)vone[u];   // v_fma_mix_f32 pattern
    }
#pragma unroll
    for (int u = 0; u < 8; ++u) {
        acc[u] += __shfl_xor(acc[u], 16);
        acc[u] += __shfl_xor(acc[u], 32);
    }
    if (grp == 0) {
        float4 b0 = *(const float4*)(bias + sl * 8);
        float4 b1 = *(const float4*)(bias + sl * 8 + 4);
        float o[8];
        o[0] = acc[0] * ndv + b0.x; o[1] = acc[1] * ndv + b0.y;
        o[2] = acc[2] * ndv + b0.z; o[3] = acc[3] * ndv + b0.w;
        o[4] = acc[4] * ndv + b1.x; o[5] = acc[5] * ndv + b1.y;
        o[6] = acc[6] * ndv + b1.z; o[7] = acc[7] * ndv + b1.w;
        if (OUT16) {
            float nsv = rsqrtf(fmaxf((float)pad[node * PS], 1.f));
            h8v hv;
#pragma unroll
            for (int u = 0; u < 8; ++u) hv[u] = (_Float16)(fmaxf(o[u], 0.f) * nsv);
            *(h8v*)(zh + (size_t)node * D + sl * 8) = hv;
        } else {
            *(float4*)(zf + (size_t)node * D + sl * 8) = make_float4(o[0], o[1], o[2], o[3]);
            *(float4*)(zf + (size_t)node * D + sl * 8 + 4) = make_float4(o[4], o[5], o[6], o[7]);
        }
    }
}

// ---------------- z transpose: zt[col][node] fp16, zero-padded to NP2 ------------------
__global__ void __launch_bounds__(256) ztrans_kernel(const float* __restrict__ z1,
                                                     const float* __restrict__ z2,
                                                     _Float16* __restrict__ zt1,
                                                     _Float16* __restrict__ zt2, int N) {
    __shared__ _Float16 tile[64][132];
    int g = blockIdx.y;
    const float* z = g ? z2 : z1;
    _Float16* zt = g ? zt2 : zt1;
    int n0 = blockIdx.x * 64;
    int tid = threadIdx.x;
#pragma unroll
    for (int it = 0; it < 8; ++it) {
        int idx = it * 256 + tid;
        int row = idx >> 5;
        int c4 = (idx & 31) * 4;
        int gr = n0 + row;
        float4 v = make_float4(0.f, 0.f, 0.f, 0.f);
        if (gr < N) v = *(const float4*)&z[(size_t)gr * D + c4];
        h4v h = {(_Float16)v.x, (_Float16)v.y, (_Float16)v.z, (_Float16)v.w};
        *(h4v*)&tile[row][c4] = h;
    }
    __syncthreads();
    int col = tid >> 1, half = tid & 1;
    _Float16 buf[32];
#pragma unroll
    for (int k = 0; k < 32; ++k) buf[k] = tile[half * 32 + k][col];
    _Float16* dst = zt + (size_t)col * NP2 + n0 + half * 32;
#pragma unroll
    for (int c = 0; c < 4; ++c) *(h8v*)(dst + c * 8) = *(const h8v*)&buf[c * 8];
}

// ---------------- Gram via MFMA, 4-way column split; dense per-block stats -------------
__global__ void __launch_bounds__(512) gram_mfma(const _Float16* __restrict__ zt1,
                                                 const _Float16* __restrict__ zt2,
                                                 float* __restrict__ part,
                                                 float* __restrict__ statpart) {
    int tid = threadIdx.x;
    int w = tid >> 6, l = tid & 63;
    int l16 = l & 15, lg = l >> 4;
    int cy = blockIdx.y * 32;
    f4v acc[2];
    acc[0] = (f4v){0.f, 0.f, 0.f, 0.f};
    acc[1] = (f4v){0.f, 0.f, 0.f, 0.f};
    float sA = 0.f, qA = 0.f, sB = 0.f, qB = 0.f;
    int r0 = blockIdx.x * RPB;
    const _Float16* ap = zt1 + (size_t)(w * 16 + l16) * NP2 + lg * 8;
    const _Float16* bp0 = zt2 + (size_t)(cy + l16) * NP2 + lg * 8;
    const _Float16* bp1 = zt2 + (size_t)(cy + 16 + l16) * NP2 + lg * 8;
#pragma unroll 1
    for (int ks = 0; ks < RPB / 32; ++ks) {
        int k0 = r0 + ks * 32;
        h8v a = *(const h8v*)(ap + k0);
        h8v b0 = *(const h8v*)(bp0 + k0);
        h8v b1 = *(const h8v*)(bp1 + k0);
        if (blockIdx.y == 0) {
#pragma unroll
            for (int j = 0; j < 8; ++j) {
                float f = (float)a[j];
                sA += f;
                qA += f * f;
            }
        }
        if (w < 2) {
            h8v bb = w ? b1 : b0;
#pragma unroll
            for (int j = 0; j < 8; ++j) {
                float f = (float)bb[j];
                sB += f;
                qB += f * f;
            }
        }
        acc[0] = __builtin_amdgcn_mfma_f32_16x16x32_f16(a, b0, acc[0], 0, 0, 0);
        acc[1] = __builtin_amdgcn_mfma_f32_16x16x32_f16(a, b1, acc[1], 0, 0, 0);
    }
    float* pb = part + (size_t)blockIdx.x * (D * D);
#pragma unroll
    for (int n = 0; n < 2; ++n)
#pragma unroll
        for (int r = 0; r < 4; ++r)
            pb[(w * 16 + lg * 4 + r) * D + cy + n * 16 + l16] = acc[n][r];
    float* sp = statpart + (size_t)blockIdx.x * 512;
    if (blockIdx.y == 0) {
        sA += __shfl_xor(sA, 16); sA += __shfl_xor(sA, 32);
        qA += __shfl_xor(qA, 16); qA += __shfl_xor(qA, 32);
        if (lg == 0) {
            int row = w * 16 + l16;
            sp[row] = sA;
            sp[D + row] = qA;
        }
    }
    if (w < 2) {
        sB += __shfl_xor(sB, 16); sB += __shfl_xor(sB, 32);
        qB += __shfl_xor(qB, 16); qB += __shfl_xor(qB, 32);
        if (lg == 0) {
            int col = cy + w * 16 + l16;
            sp[2 * D + col] = sB;
            sp[3 * D + col] = qB;
        }
    }
}

// ---------------- single-pass partial reduce (no atomics, no memset) -------------------
__global__ void reduce_part(const float* __restrict__ part, float* __restrict__ Csum) {
    int e = blockIdx.x * 256 + threadIdx.x;
    float s = 0.f;
#pragma unroll 8
    for (int p = 0; p < GP; ++p)
        s += __builtin_nontemporal_load(&part[(size_t)p * (D * D) + e]);
    Csum[e] = s;
}

// ---------------- fused: stats-reduce + normalize + row/col means + masks + write ------
__global__ void __launch_bounds__(1024) corrmask_kernel(const float* __restrict__ Csum,
                                                        const float* __restrict__ statpart,
                                                        const float* __restrict__ roff,
                                                        const float* __restrict__ coff,
                                                        float* __restrict__ out, int N) {
    __shared__ float cL[D * D];
    __shared__ float statsh[512];
    __shared__ float m1s[D], i1s[D], m2s[D], i2s[D];
    __shared__ float rowpart[D][2];
    __shared__ float colpart[8][D];
    __shared__ float rms[D], cms[D];
    int t = threadIdx.x;
    int j = t & 127, rg = t >> 7;
    if (t < 512) {
        float s = 0.f;
        for (int p = 0; p < GP; ++p) s += statpart[(size_t)p * 512 + t];
        statsh[t] = s;
    }
    __syncthreads();
    float fn = (float)N;
    if (t < D) {
        float m1 = statsh[t] / fn;
        float v1 = fmaxf((statsh[D + t] - fn * m1 * m1) / (fn - 1.f), 0.f);
        m1s[t] = m1;
        i1s[t] = 1.f / (sqrtf(v1) + EPS);
    } else if (t < 2 * D) {
        int jj = t - D;
        float m2 = statsh[2 * D + jj] / fn;
        float v2 = fmaxf((statsh[3 * D + jj] - fn * m2 * m2) / (fn - 1.f), 0.f);
        m2s[jj] = m2;
        i2s[jj] = 1.f / (sqrtf(v2) + EPS);
    }
    __syncthreads();
    float b = m2s[j], vj = i2s[j];
    float invfn = 1.f / fn;
    float colacc = 0.f;
    for (int k = 0; k < 16; ++k) {
        int i = rg * 16 + k;
        int e = i * D + j;
        float c = (Csum[e] - fn * m1s[i] * b) * (i1s[i] * vj) * invfn;
        cL[e] = c;
        float a = fabsf(c);
        colacc += a;
        for (int o = 1; o < 64; o <<= 1) a += __shfl_xor(a, o);
        if ((j & 63) == 0) rowpart[i][j >> 6] = a;
    }
    colpart[rg][j] = colacc;
    __syncthreads();
    if (t < D) {
        float rs = rowpart[t][0] + rowpart[t][1];
        float rm = 1.f / (1.f + expf(-SCALE * (rs / (float)D + roff[t] - THRESH)));
        rms[t] = rm;
        out[D * D + t] = rm;
    } else if (t < 2 * D) {
        int jj = t - D;
        float cs = 0.f;
#pragma unroll
        for (int g2 = 0; g2 < 8; ++g2) cs += colpart[g2][jj];
        float cm = 1.f / (1.f + expf(-SCALE * (cs / (float)D + coff[jj] - THRESH)));
        cms[jj] = cm;
        out[D * D + D + jj] = cm;
    }
    __syncthreads();
    for (int k = 0; k < 16; ++k) {
        int i = rg * 16 + k;
        int e = i * D + j;
        out[e] = cL[e] * rms[i] * cms[j];
    }
}

extern "C" void kernel_launch(void* const* d_in, const int* in_sizes, int n_in,
                              void* d_out, int out_size, void* d_ws, size_t ws_size,
                              hipStream_t stream) {
    const float* x1 = (const float*)d_in[0];
    const float* x2 = (const float*)d_in[1];
    const int* src1 = (const int*)d_in[2];
    const int* dst1 = (const int*)d_in[3];
    const int* src2 = (const int*)d_in[4];
    const int* dst2 = (const int*)d_in[5];
    const float* W1 = (const float*)d_in[6];
    const float* b1 = (const float*)d_in[7];
    const float* W2 = (const float*)d_in[8];
    const float* b2 = (const float*)d_in[9];
    const float* roff = (const float*)d_in[10];
    const float* coff = (const float*)d_in[11];

    const int N = in_sizes[0] / D;
    const int E = in_sizes[2];

    float* ws = (float*)d_ws;
    // phase-1:
    unsigned int* staging = (unsigned int*)ws;                         // 19.2 MB
    unsigned short* bucket1 =
        (unsigned short*)(staging + (size_t)2 * NRANGE * BB * RNGP);   // 6 MB
    unsigned short* bucket2 = bucket1 + (size_t)N * CAP;               // 6 MB
    int* pad1 = (int*)(bucket2 + (size_t)N * CAP);                     // 0.4 MB
    int* pad2 = pad1 + (size_t)N * PS;                                 // 0.4 MB
    _Float16* Wt1 = (_Float16*)(pad2 + (size_t)N * PS);                // 32 KB
    _Float16* Wt2 = Wt1 + D * D;                                       // 32 KB
    _Float16* y1 = Wt2 + D * D;                                        // (N+1)*D fp16
    _Float16* y2 = y1 + (size_t)(N + 1) * D;                           // (N+1)*D fp16
    // phase-2 (aliases from ws start; phase-1 dead by then except z in d_out):
    _Float16* zt1 = (_Float16*)ws;                                     // 13.4 MB
    _Float16* zt2 = zt1 + (size_t)D * NP2;                             // 13.4 MB
    float* part = (float*)(zt2 + (size_t)D * NP2);                     // 3.1 MB
    float* Csum = part + (size_t)GP * D * D;                           // 64 KB
    float* statpart = Csum + D * D;                                    // 96 KB

    float* out = (float*)d_out;
    float* z1 = out + D * D + 2 * D;
    float* z2 = z1 + (size_t)N * D;
    _Float16* hp1 = (_Float16*)z1;   // fp16 h' scratch in z regions (dead by gather2)
    _Float16* hp2 = (_Float16*)z2;

    // atomic-free CSR build: count -> scan -> place
    count_kernel<<<2 * NRANGE * BB, 256, 0, stream>>>(src1, dst1, src2, dst2, staging, E, N);
    scan_kernel<<<(2 * N + 255) / 256, 256, 0, stream>>>(staging, pad1, pad2, N);
    place_kernel<<<2 * NRANGE * BB, 256, 0, stream>>>(src1, dst1, src2, dst2, staging,
                                                      bucket1, bucket2, E, N);
    wtrans_kernel<<<2 * D * D / 256 + 1, 256, 0, stream>>>(W1, W2, Wt1, Wt2, y1, y2, N);

    // GNN layers, both graphs per launch
    const int gblk = (N + 127) / 128;
    {
        dim3 gg(gblk, 2), ga((N + 3) / 4, 2);
        gemm_ns<true><<<gg, 256, 0, stream>>>(x1, x2, nullptr, nullptr, pad1, pad2,
                                              Wt1, y1, y2, N);
        gather_kernel<true><<<ga, 256, 0, stream>>>(bucket1, bucket2, pad1, pad2, y1, y2,
                                                    b1, nullptr, nullptr, hp1, hp2, N);
        gemm_ns<false><<<gg, 256, 0, stream>>>(nullptr, nullptr, hp1, hp2, pad1, pad2,
                                               Wt2, y1, y2, N);
        gather_kernel<false><<<ga, 256, 0, stream>>>(bucket1, bucket2, pad1, pad2, y1, y2,
                                                     b2, z1, z2, nullptr, nullptr, N);
    }

    // corr phase: transpose -> MFMA gram (col-split) -> reduce -> mask
    {
        dim3 tgrid(NP2 / 64, 2);
        ztrans_kernel<<<tgrid, 256, 0, stream>>>(z1, z2, zt1, zt2, N);
    }
    {
        dim3 ggrid(GP, CSPLIT);
        gram_mfma<<<ggrid, 512, 0, stream>>>(zt1, zt2, part, statpart);
    }
    reduce_part<<<64, 256, 0, stream>>>(part, Csum);
    corrmask_kernel<<<1, 1024, 0, stream>>>(Csum, statpart, roff, coff, out, N);
}